// Round 7
// baseline (2604.978 us; speedup 1.0000x reference)
//
#include <hip/hip_runtime.h>
#include <math.h>

typedef unsigned short u16;
typedef unsigned int   u32;
typedef __bf16 bf16x8 __attribute__((ext_vector_type(8)));
typedef float  f32x4  __attribute__((ext_vector_type(4)));

__device__ __forceinline__ float b2f(u16 u) {
    unsigned v = ((unsigned)u) << 16;
    return __uint_as_float(v);
}
__device__ __forceinline__ u16 f2b(float f) {
    unsigned x = __float_as_uint(f);
    unsigned r = (x + 0x7fffu + ((x >> 16) & 1u)) >> 16;  // RNE
    return (u16)r;
}
__device__ __forceinline__ void fsplit(float v, u16& h, u16& l) {
    h = f2b(v);
    l = f2b(v - b2f(h));
}
__device__ __forceinline__ float h2f(u16 u) {
    union { u16 us; _Float16 h; } c; c.us = u; return (float)c.h;
}
__device__ __forceinline__ u16 f2h(float f) {
    union { u16 us; _Float16 h; } c; c.h = (_Float16)f; return c.us;
}
__device__ __forceinline__ float ldx(const void* p, size_t i, int f32m) {
    return f32m ? ((const float*)p)[i] : b2f(((const u16*)p)[i]);
}

// Async 16B global->LDS DMA (no VGPR transit; tracked by vmcnt; drained by
// the implicit vmcnt(0) before s_barrier in __syncthreads).
__device__ __forceinline__ void gld16(u16* l, const u16* g) {
    __builtin_amdgcn_global_load_lds(
        (const __attribute__((address_space(1))) unsigned int*)g,
        (__attribute__((address_space(3))) unsigned int*)l,
        16, 0, 0);
}

// Bank swizzle for linear [row][32-u16] staging tiles (64B rows).
// Writer: thread t (chunk t = row*4+ch) loads global channel-quarter
// (t&3)^swz(row); reader fetches k-quarter qd at slot qd^swz(row).
// Gives 2-way (free) bank pattern on ds_read_b128; involution; global
// source stays coalesced (per-row permutation of 16B chunks only).
__device__ __forceinline__ int swz(int row) {
    return (row & 3) ^ ((row >> 2) & 3);
}

// flag[0] = input dtype (1=f32, 0=bf16).
__global__ void detect_dtype(const u16* __restrict__ x0, int* flag)
{
    int lane = threadIdx.x;  // 64 threads
    int bad = 0;
    for (int i = lane; i < 1024; i += 64) {
        float v = b2f(x0[i]);
        if (!(fabsf(v) < 32768.f)) bad = 1;
    }
    unsigned long long m = __ballot(bad);
    if (lane == 0) flag[0] = (m != 0ULL) ? 1 : 0;
}

// ---------------------------------------------------------------------------
// Pre-split ALL weights (hi/lo bf16 planes) + biases/bn (f32) into ws.
// Packed weight layout (elem offsets):
//   Wr1[96x192]@0  Wr2[192x96]@18432  Wqv[384x192]@36864  Wcf[192x960]@110592
//   We1[96x192]@294912  We2[192x96]@313344  Wk[192x192]@331776   (total 368640)
// Bias f32 layout: br1@0 br2@96 bqv@288 bcf@672 be1@864 be2@960 bk@1152
//   bns@1344 bnt@1536  (total 1728)
// ---------------------------------------------------------------------------
struct SrcPtrs {
    const void *wr1, *br1, *wr2, *br2, *wq, *bq, *wv, *bv, *wcf, *bcf;
    const void *we1, *be1, *we2, *be2, *wk1, *bk1, *wk2, *bk2, *wk3, *bk3;
    const void *bns, *bnt;
};
__global__ void pack_weights(SrcPtrs S, u16* __restrict__ Wh, u16* __restrict__ Wl,
                             float* __restrict__ Bias, const int* __restrict__ dflag)
{
    const int f32m = *dflag;
    int idx = blockIdx.x * 256 + threadIdx.x;
    if (idx < 368640) {
        const void* src; size_t si;
        if (idx < 18432)       { src = S.wr1; si = idx; }
        else if (idx < 36864)  { src = S.wr2; si = idx - 18432; }
        else if (idx < 110592) {
            int r = idx - 36864, o = r / 192, c = r % 192;
            if (o < 192) { src = S.wq; si = (size_t)o * 192 + c; }
            else         { src = S.wv; si = (size_t)(o - 192) * 192 + c; }
        }
        else if (idx < 294912) { src = S.wcf; si = idx - 110592; }
        else if (idx < 313344) { src = S.we1; si = idx - 294912; }
        else if (idx < 331776) { src = S.we2; si = idx - 313344; }
        else {
            int r = idx - 331776, o = r / 192, c = r % 192;
            src = (o < 64) ? S.wk1 : ((o < 128) ? S.wk2 : S.wk3);
            si = (size_t)(o & 63) * 192 + c;
        }
        u16 h, l; fsplit(ldx(src, si, f32m), h, l);
        Wh[idx] = h; Wl[idx] = l;
    } else if (idx < 370368) {
        int b = idx - 368640; const void* src; size_t si;
        if (b < 96)        { src = S.br1; si = b; }
        else if (b < 288)  { src = S.br2; si = b - 96; }
        else if (b < 672)  { int r = b - 288;
                             if (r < 192) { src = S.bq; si = r; }
                             else         { src = S.bv; si = r - 192; } }
        else if (b < 864)  { src = S.bcf; si = b - 672; }
        else if (b < 960)  { src = S.be1; si = b - 864; }
        else if (b < 1152) { src = S.be2; si = b - 960; }
        else if (b < 1344) { int r = b - 1152;
                             src = (r < 64) ? S.bk1 : ((r < 128) ? S.bk2 : S.bk3);
                             si = r & 63; }
        else if (b < 1536) { src = S.bns; si = b - 1344; }
        else               { src = S.bnt; si = b - 1536; }
        Bias[b] = ldx(src, si, f32m);
    }
}

// ---------------------------------------------------------------------------
// 1D resize tap tables per level {0,2,3,4}: 96 outputs x <=4 taps, weights
// pre-normalized (renorm folded in).  jax.image.resize triangle kernel.
// ---------------------------------------------------------------------------
__global__ void build_tables(float* __restrict__ wtab, int* __restrict__ jtab)
{
    int t = threadIdx.x;            // 384 = 4 levels x 96 outputs
    if (t >= 384) return;
    int li = t / 96, o = t % 96;
    const int ins[4] = {192, 48, 24, 12};
    int in = ins[li];
    float scale = (float)in / 96.0f;
    float ksc = fmaxf(scale, 1.0f);
    float cc = (o + 0.5f) * scale - 0.5f;
    float w[4] = {0.f, 0.f, 0.f, 0.f};
    int   j[4] = {0, 0, 0, 0};
    int n = 0; float s = 0.f;
    int jl = (int)floorf(cc - ksc), jh = (int)floorf(cc + ksc) + 1;
    for (int jj = jl; jj <= jh; jj++) {
        if (jj < 0 || jj >= in) continue;
        float ww = 1.0f - fabsf((float)jj - cc) / ksc;
        if (ww <= 0.f) continue;
        if (n < 4) { w[n] = ww; j[n] = jj; s += ww; n++; }
    }
    for (int i = 0; i < 4; i++) {
        wtab[li * 384 + o * 4 + i] = w[i] / s;
        jtab[li * 384 + o * 4 + i] = j[i];
    }
}

// ---------------------------------------------------------------------------
// LDS-tiled transpose of one level: channel-major [b][192][HW] -> pixel-major.
// ---------------------------------------------------------------------------
template<int SPLIT>
__launch_bounds__(256)
__global__ void transpose_in(const void* __restrict__ src, int HW,
                             u32* __restrict__ P, u16* __restrict__ Xh,
                             u16* __restrict__ Xl, const int* __restrict__ dflag)
{
    __shared__ float t[32][33];
    const int f32m = *dflag;
    const int b  = blockIdx.z;
    const int c0 = blockIdx.y * 32;
    const int p0 = blockIdx.x * 32;
    const int tid = threadIdx.x;
#pragma unroll
    for (int it = 0; it < 4; it++) {
        int i = it * 256 + tid;
        int pl = i & 31, cl = i >> 5;
        int p = p0 + pl;
        float v = 0.f;
        if (p < HW) v = ldx(src, ((size_t)(b * 192 + c0 + cl)) * HW + p, f32m);
        t[pl][cl] = v;
    }
    __syncthreads();
#pragma unroll
    for (int it = 0; it < 4; it++) {
        int i = it * 256 + tid;
        int cl = i & 31, pl = i >> 5;
        int p = p0 + pl;
        if (p >= HW) continue;
        float v = t[pl][cl];
        u16 h, l; fsplit(v, h, l);
        if constexpr (SPLIT) {
            size_t oi = ((size_t)((4 + b) * 9216 + p)) * 192 + c0 + cl;
            Xh[oi] = h; Xl[oi] = l;
        } else {
            P[((size_t)b * HW + p) * 192 + c0 + cl] = (u32)h | ((u32)l << 16);
        }
    }
}

// ---------------------------------------------------------------------------
// Table-driven bilinear resize.  TAPS=4: level 0.  TAPS=2: levels 2,3,4.
// ---------------------------------------------------------------------------
template<int TAPS>
__launch_bounds__(256)
__global__ void upsample2(const u32* __restrict__ Pa, const u32* __restrict__ Pb,
                          const u32* __restrict__ Pc,
                          const float* __restrict__ wtab, const int* __restrict__ jtab,
                          u16* __restrict__ Xh, u16* __restrict__ Xl)
{
    int li, b, l, in;
    const u32* P;
    if constexpr (TAPS == 4) {
        li = 0; b = blockIdx.y; l = 0; in = 192; P = Pa;
    } else {
        int yi = blockIdx.y;               // 12 = 3 levels x 4 batch
        li = 1 + (yi >> 2); b = yi & 3;
        const int lvl[4] = {0, 2, 3, 4};
        const int ins[4] = {192, 48, 24, 12};
        l = lvl[li]; in = ins[li];
        P = (li == 1) ? Pa : ((li == 2) ? Pb : Pc);
    }
    int gid = blockIdx.x * 256 + threadIdx.x;   // 9216*192
    int c = gid % 192;
    int p = gid / 192;
    int y = p / 96, x = p % 96;
    const float* wt = wtab + li * 384;
    const int*   jt = jtab + li * 384;

    size_t ib = (size_t)b * in * in * 192 + c;
    float a = 0.f;
#pragma unroll
    for (int iy = 0; iy < TAPS; iy++) {
        float wy = wt[y * 4 + iy];
        size_t rb = ib + (size_t)(jt[y * 4 + iy] * in) * 192;
        float ax = 0.f;
#pragma unroll
        for (int ix = 0; ix < TAPS; ix++) {
            u32 u = P[rb + jt[x * 4 + ix] * 192];
            ax += wt[x * 4 + ix] * (b2f((u16)u) + b2f((u16)(u >> 16)));
        }
        a += wy * ax;
    }
    size_t oi = ((size_t)(l * 4 + b) * 9216 + p) * 192 + c;
    u16 h, lo; fsplit(a, h, lo);
    Xh[oi] = h; Xl[oi] = lo;
}

// ---------------------------------------------------------------------------
// Split-precision conv1x1 GEMM (cat_fuse only now) — R2 single-buffered form.
// ---------------------------------------------------------------------------
template<int MT, int NT, int ACT, int MODE, int OUT>
__launch_bounds__(256)
__global__ void conv_gemm(const u16* __restrict__ Ah, const u16* __restrict__ Al,
                          const u16* __restrict__ Wh, const u16* __restrict__ Wl,
                          const float* __restrict__ Bias,
                          int woff, int boff, int K, int O,
                          u16* __restrict__ out0, u16* __restrict__ out1)
{
    constexpr int BM = MT * 64, BN = NT * 16;
    __shared__ u16 Ash[BM * 40];
    __shared__ u16 Asl[BM * 40];
    __shared__ u16 Bsh[BN * 40];
    __shared__ u16 Bsl[BN * 40];

    const int tid  = threadIdx.x;
    const int lane = tid & 63, wave = tid >> 6;
    const int qd   = lane >> 4, ln = lane & 15;
    const int p0   = blockIdx.x * BM;
    const int img  = blockIdx.z;
    const int M    = 9216;

    f32x4 acc[MT][NT];
#pragma unroll
    for (int mt = 0; mt < MT; mt++)
#pragma unroll
        for (int j = 0; j < NT; j++) acc[mt][j] = (f32x4){0.f, 0.f, 0.f, 0.f};

    for (int kb = 0; kb < K; kb += 32) {
#pragma unroll
        for (int i = 0; i < MT; i++) {
            int idx = i * 256 + tid;
            int row = idx >> 2, ch = idx & 3;
            size_t base;
            if constexpr (MODE == 2) {
                int l = kb / 192, c0 = kb - l * 192 + ch * 8;
                base = ((size_t)((l * 4 + img) * M + p0 + row)) * 192 + c0;
            } else {
                base = ((size_t)(img * M + p0 + row)) * (size_t)K + kb + ch * 8;
            }
            *(float4*)&Ash[row * 40 + ch * 8] = *(const float4*)(Ah + base);
            *(float4*)&Asl[row * 40 + ch * 8] = *(const float4*)(Al + base);
        }
        constexpr int BI = (BN * 4) / 256;
#pragma unroll
        for (int i = 0; i < BI; i++) {
            int idx = i * 256 + tid;
            int row = idx >> 2, ch = idx & 3;
            size_t wb = (size_t)woff + (size_t)row * K + kb + ch * 8;
            *(float4*)&Bsh[row * 40 + ch * 8] = *(const float4*)(Wh + wb);
            *(float4*)&Bsl[row * 40 + ch * 8] = *(const float4*)(Wl + wb);
        }
        __syncthreads();
        bf16x8 ah[MT], al[MT];
#pragma unroll
        for (int mt = 0; mt < MT; mt++) {
            ah[mt] = *(const bf16x8*)&Ash[(wave * MT * 16 + mt * 16 + ln) * 40 + qd * 8];
            al[mt] = *(const bf16x8*)&Asl[(wave * MT * 16 + mt * 16 + ln) * 40 + qd * 8];
        }
#pragma unroll
        for (int j = 0; j < NT; j++) {
            bf16x8 bh = *(const bf16x8*)&Bsh[(j * 16 + ln) * 40 + qd * 8];
            bf16x8 bl = *(const bf16x8*)&Bsl[(j * 16 + ln) * 40 + qd * 8];
#pragma unroll
            for (int mt = 0; mt < MT; mt++) {
                acc[mt][j] = __builtin_amdgcn_mfma_f32_16x16x32_bf16(ah[mt], bh, acc[mt][j], 0, 0, 0);
                acc[mt][j] = __builtin_amdgcn_mfma_f32_16x16x32_bf16(ah[mt], bl, acc[mt][j], 0, 0, 0);
                acc[mt][j] = __builtin_amdgcn_mfma_f32_16x16x32_bf16(al[mt], bh, acc[mt][j], 0, 0, 0);
            }
        }
        __syncthreads();
    }

#pragma unroll
    for (int mt = 0; mt < MT; mt++) {
#pragma unroll
        for (int j = 0; j < NT; j++) {
            int o = j * 16 + ln;
            float bvf = Bias[boff + o];
#pragma unroll
            for (int r = 0; r < 4; r++) {
                int prow = p0 + wave * MT * 16 + mt * 16 + qd * 4 + r;
                float v = acc[mt][j][r] + bvf;
                if constexpr (ACT == 1) v = fmaxf(v, 0.f);
                if constexpr (OUT == 0) {
                    size_t oidx = ((size_t)(img * M + prow)) * (size_t)O + o;
                    u16 h, l; fsplit(v, h, l);
                    out0[oidx] = h; out1[oidx] = l;
                } else if constexpr (OUT == 1) {
                    out0[((size_t)(img * M + prow)) * (size_t)O + o] = f2h(v);
                } else {
                    size_t pb = ((size_t)(img * M + prow)) * 192;
                    if (o < 192) out0[pb + o] = f2h(v);
                    else         out1[pb + o - 192] = f2h(v);
                }
            }
        }
    }
}

// ---------------------------------------------------------------------------
// Fused 192 -> 96(ACT1) -> 192 MLP (emb), async-DMA staging + optional Keys
// tail-GEMM (KEYS=1): epilogue La also lands in a byte-XOR-swizzled X2 LDS
// tile, then Keys = Wk x La (O=192, 2 passes x 96 outs, dbuf async W3).
// Replaces the standalone keys conv_gemm (La never round-trips via global).
// Per-element kb order + hh/hl/lh sequence match the old kernel exactly and
// X2 holds the same post-fsplit h/l bits -> bit-identical Keys.
// LDS map (u16), declared 38912 = 77824 B -> 2 blocks/CU:
//   phase1: Hh@0 Hl@6656 | SA[c]@13312+c*10240
//   phase2: B2[c]@13312+c*12288
//   phase3: X2h@0 X2l@12288 | B3[c]@24576+c*6144   (B2/SA dead)
// ---------------------------------------------------------------------------
template<int ACT1, int MODE2, int KEYS>
__launch_bounds__(256)
__global__ void fused_mlp(const u16* __restrict__ Ah, const u16* __restrict__ Al,
                          const u16* __restrict__ Wh, const u16* __restrict__ Wl,
                          const float* __restrict__ Bias,
                          int w1off, int b1off, int w2off, int b2off,
                          u16* __restrict__ outh, u16* __restrict__ outl,
                          u16* __restrict__ Keys)
{
    __shared__ __align__(16) u16 LDS[38912];
    u16* Hh = LDS;              // 64*104
    u16* Hl = LDS + 6656;

    const int tid  = threadIdx.x;
    const int lane = tid & 63, wave = tid >> 6;
    const int qd   = lane >> 4, ln = lane & 15;
    const int p0   = blockIdx.x * 64;
    const int img  = blockIdx.z;
    const int M    = 9216;
    const int irow = tid >> 2, ich = tid & 3;

    auto g1issue = [&](int kb, int c) {
        u16* SA = LDS + 13312 + c * 10240;
        int ch = ich ^ swz(irow);
        size_t ga = ((size_t)(img * M + p0 + irow)) * 192 + kb + ch * 8;
        gld16(SA + wave * 512,        Ah + ga);
        gld16(SA + 2048 + wave * 512, Al + ga);
        size_t gb = (size_t)w1off + (size_t)irow * 192 + kb + ch * 8;
        gld16(SA + 4096 + wave * 512, Wh + gb);
        gld16(SA + 7168 + wave * 512, Wl + gb);
        if (tid < 128) {
            int r2 = 64 + irow;
            int ch2 = ich ^ swz(r2);
            size_t gb2 = (size_t)w1off + (size_t)r2 * 192 + kb + ch2 * 8;
            gld16(SA + 6144 + wave * 512, Wh + gb2);
            gld16(SA + 9216 + wave * 512, Wl + gb2);
        }
    };
    auto g2issue = [&](int kb, int c) {
        u16* B2 = LDS + 13312 + c * 12288;
#pragma unroll
        for (int i = 0; i < 3; i++) {
            int r = i * 64 + irow;
            int ch = ich ^ swz(r);
            size_t g = (size_t)w2off + (size_t)r * 96 + kb + ch * 8;
            gld16(B2 + i * 2048 + wave * 512,        Wh + g);
            gld16(B2 + 6144 + i * 2048 + wave * 512, Wl + g);
        }
    };
    auto g3issue = [&](int s, int c) {          // s = pass*6 + t, 0..11
        int p = s / 6, kb = (s - p * 6) * 32;
        u16* B3 = LDS + 24576 + c * 6144;
        int ch = ich ^ swz(irow);
        size_t g = (size_t)331776 + (size_t)(p * 96 + irow) * 192 + kb + ch * 8;
        gld16(B3 + wave * 512,        Wh + g);
        gld16(B3 + 3072 + wave * 512, Wl + g);
        if (tid < 128) {
            int r2 = 64 + irow;
            int ch2 = ich ^ swz(r2);
            size_t g2 = (size_t)331776 + (size_t)(p * 96 + r2) * 192 + kb + ch2 * 8;
            gld16(B3 + 2048 + wave * 512, Wh + g2);
            gld16(B3 + 5120 + wave * 512, Wl + g2);
        }
    };

    // ---------------- GEMM1: A -> hidden(96), ACT1 ----------------
    f32x4 acc1[6];
#pragma unroll
    for (int j = 0; j < 6; j++) acc1[j] = (f32x4){0.f, 0.f, 0.f, 0.f};

    g1issue(0, 0);
    __syncthreads();
#pragma unroll 2
    for (int kb = 0; kb < 192; kb += 32) {
        int cur = (kb >> 5) & 1;
        if (kb + 32 < 192) g1issue(kb + 32, cur ^ 1);
        const u16* SA = LDS + 13312 + cur * 10240;
        int arow = wave * 16 + ln;
        int asl = arow * 32 + ((qd ^ swz(arow)) << 3);
        bf16x8 ah = *(const bf16x8*)&SA[asl];
        bf16x8 al = *(const bf16x8*)&SA[2048 + asl];
#pragma unroll
        for (int j = 0; j < 6; j++) {
            int brow = j * 16 + ln;
            int bsl = brow * 32 + ((qd ^ swz(brow)) << 3);
            bf16x8 bh = *(const bf16x8*)&SA[4096 + bsl];
            bf16x8 bl = *(const bf16x8*)&SA[7168 + bsl];
            acc1[j] = __builtin_amdgcn_mfma_f32_16x16x32_bf16(ah, bh, acc1[j], 0, 0, 0);
            acc1[j] = __builtin_amdgcn_mfma_f32_16x16x32_bf16(ah, bl, acc1[j], 0, 0, 0);
            acc1[j] = __builtin_amdgcn_mfma_f32_16x16x32_bf16(al, bh, acc1[j], 0, 0, 0);
        }
        __syncthreads();
    }

    g2issue(0, 0);              // hide W2 step-0 latency under the H-write
#pragma unroll
    for (int j = 0; j < 6; j++) {
        int o = j * 16 + ln;
        float bvf = Bias[b1off + o];
#pragma unroll
        for (int r = 0; r < 4; r++) {
            float v = acc1[j][r] + bvf;
            if constexpr (ACT1 == 1) v = fmaxf(v, 0.f);
            if constexpr (ACT1 == 2) v = 0.5f * v * (1.f + erff(v * 0.70710678118654752f));
            u16 h, l; fsplit(v, h, l);
            int row = wave * 16 + qd * 4 + r;
            Hh[row * 104 + o] = h;
            Hl[row * 104 + o] = l;
        }
    }
    __syncthreads();

    // ---------------- GEMM2: hidden(LDS) -> out(192) ----------------
    f32x4 acc2[12];
#pragma unroll
    for (int j = 0; j < 12; j++) acc2[j] = (f32x4){0.f, 0.f, 0.f, 0.f};

#pragma unroll
    for (int kb = 0; kb < 96; kb += 32) {
        int cur = (kb >> 5) & 1;
        if (kb + 32 < 96) g2issue(kb + 32, cur ^ 1);
        const u16* B2 = LDS + 13312 + cur * 12288;
        bf16x8 ah = *(const bf16x8*)&Hh[(wave * 16 + ln) * 104 + kb + qd * 8];
        bf16x8 al = *(const bf16x8*)&Hl[(wave * 16 + ln) * 104 + kb + qd * 8];
#pragma unroll
        for (int j = 0; j < 12; j++) {
            int brow = j * 16 + ln;
            int bsl = brow * 32 + ((qd ^ swz(brow)) << 3);
            bf16x8 bh = *(const bf16x8*)&B2[bsl];
            bf16x8 bl = *(const bf16x8*)&B2[6144 + bsl];
            acc2[j] = __builtin_amdgcn_mfma_f32_16x16x32_bf16(ah, bh, acc2[j], 0, 0, 0);
            acc2[j] = __builtin_amdgcn_mfma_f32_16x16x32_bf16(ah, bl, acc2[j], 0, 0, 0);
            acc2[j] = __builtin_amdgcn_mfma_f32_16x16x32_bf16(al, bh, acc2[j], 0, 0, 0);
        }
        __syncthreads();
    }

    if constexpr (KEYS) g3issue(0, 0);   // hide Wk step-0 under the epilogue

    // ---- epilogue: La -> global (+X2 LDS when KEYS) ----
    u16* X2h = LDS;             // 64*192, byte-XOR swizzled (R2 scheme)
    u16* X2l = LDS + 12288;
#pragma unroll
    for (int j = 0; j < 12; j++) {
        int o = j * 16 + ln;
        float bvf = Bias[b2off + o];
#pragma unroll
        for (int r = 0; r < 4; r++) {
            int row  = wave * 16 + qd * 4 + r;
            int prow = p0 + row;
            float v = acc2[j][r] + bvf;
            size_t oidx = ((size_t)(img * M + prow)) * 192 + o;
            if constexpr (MODE2 == 1) {
                float xo = b2f(outh[oidx]) + b2f(outl[oidx]);
                v = fmaxf((xo + v) * Bias[1344 + o] + Bias[1536 + o], 0.f);
            }
            u16 h, l; fsplit(v, h, l);
            outh[oidx] = h; outl[oidx] = l;
            if constexpr (KEYS) {
                int off = ((row * 192 + o) * 2) ^ ((row & 7) << 4);
                *(u16*)((char*)X2h + off) = h;
                *(u16*)((char*)X2l + off) = l;
            }
        }
    }
    if constexpr (!KEYS) return;
    __syncthreads();

    // ---- GEMM3: La(LDS) -> Keys (O=192), 2 passes x 96 outs, dbuf W3 ----
    const int arow = wave * 16 + ln;
#pragma unroll 1
    for (int pass = 0; pass < 2; pass++) {
        f32x4 acc3[6];
#pragma unroll
        for (int j = 0; j < 6; j++) acc3[j] = (f32x4){0.f, 0.f, 0.f, 0.f};

#pragma unroll 2
        for (int t6 = 0; t6 < 6; t6++) {
            int s = pass * 6 + t6;
            int cur = t6 & 1;               // 6*pass is even -> s&1 == t6&1
            if (s < 11) g3issue(s + 1, cur ^ 1);
            int kb = t6 * 32;
            int aoff = ((arow * 192 + kb + qd * 8) * 2) ^ ((arow & 7) << 4);
            bf16x8 ah = *(const bf16x8*)((const char*)X2h + aoff);
            bf16x8 al = *(const bf16x8*)((const char*)X2l + aoff);
            const u16* B3 = LDS + 24576 + cur * 6144;
#pragma unroll
            for (int j = 0; j < 6; j++) {
                int brow = j * 16 + ln;
                int bsl = brow * 32 + ((qd ^ swz(brow)) << 3);
                bf16x8 bh = *(const bf16x8*)&B3[bsl];
                bf16x8 bl = *(const bf16x8*)&B3[3072 + bsl];
                acc3[j] = __builtin_amdgcn_mfma_f32_16x16x32_bf16(ah, bh, acc3[j], 0, 0, 0);
                acc3[j] = __builtin_amdgcn_mfma_f32_16x16x32_bf16(ah, bl, acc3[j], 0, 0, 0);
                acc3[j] = __builtin_amdgcn_mfma_f32_16x16x32_bf16(al, bh, acc3[j], 0, 0, 0);
            }
            __syncthreads();
        }
#pragma unroll
        for (int j = 0; j < 6; j++) {
            int o = pass * 96 + j * 16 + ln;
            float bvf = Bias[1152 + o];                        // bk
#pragma unroll
            for (int r = 0; r < 4; r++) {
                int prow = p0 + wave * 16 + qd * 4 + r;
                Keys[((size_t)(img * M + prow)) * 192 + o] = f2h(acc3[j][r] + bvf);
            }
        }
    }
}

// ---------------------------------------------------------------------------
// FUSED residual-MLP + QV projection, async-DMA staging edition (R6, proven).
// ---------------------------------------------------------------------------
template<int WRITE_X>
__launch_bounds__(256)
__global__ void fused_res_qv(u16* __restrict__ Xh, u16* __restrict__ Xl,
                             const u16* __restrict__ Wh, const u16* __restrict__ Wl,
                             const float* __restrict__ Bias,
                             u16* __restrict__ Qf, u16* __restrict__ Vf)
{
    __shared__ __align__(16) u16 LDS[38912];
    u16* Hh = LDS;              // 64*104
    u16* Hl = LDS + 6656;

    const int tid  = threadIdx.x;
    const int lane = tid & 63, wave = tid >> 6;
    const int qd   = lane >> 4, ln = lane & 15;
    const int p0   = blockIdx.x * 64;
    const int img  = blockIdx.z;
    const int M    = 9216;
    const int irow = tid >> 2, ich = tid & 3;

    auto g1issue = [&](int kb, int c) {
        u16* SA = LDS + 13312 + c * 10240;
        int ch = ich ^ swz(irow);
        size_t ga = ((size_t)(img * M + p0 + irow)) * 192 + kb + ch * 8;
        gld16(SA + wave * 512,        Xh + ga);
        gld16(SA + 2048 + wave * 512, Xl + ga);
        size_t gb = (size_t)irow * 192 + kb + ch * 8;          // w1off = 0
        gld16(SA + 4096 + wave * 512, Wh + gb);
        gld16(SA + 7168 + wave * 512, Wl + gb);
        if (tid < 128) {
            int r2 = 64 + irow;
            int ch2 = ich ^ swz(r2);
            size_t gb2 = (size_t)r2 * 192 + kb + ch2 * 8;
            gld16(SA + 6144 + wave * 512, Wh + gb2);
            gld16(SA + 9216 + wave * 512, Wl + gb2);
        }
    };
    auto g2issue = [&](int kb, int c) {
        u16* B2 = LDS + 13312 + c * 12288;
#pragma unroll
        for (int i = 0; i < 3; i++) {
            int r = i * 64 + irow;
            int ch = ich ^ swz(r);
            size_t g = (size_t)18432 + (size_t)r * 96 + kb + ch * 8;   // w2off
            gld16(B2 + i * 2048 + wave * 512,        Wh + g);
            gld16(B2 + 6144 + i * 2048 + wave * 512, Wl + g);
        }
    };
    auto g3issue = [&](int s, int c) {          // s = pass*6 + t, 0..23
        int p = s / 6, kb = (s - p * 6) * 32;
        u16* B3 = LDS + 24576 + c * 6144;
        int ch = ich ^ swz(irow);
        size_t g = (size_t)36864 + (size_t)(p * 96 + irow) * 192 + kb + ch * 8;
        gld16(B3 + wave * 512,        Wh + g);
        gld16(B3 + 3072 + wave * 512, Wl + g);
        if (tid < 128) {
            int r2 = 64 + irow;
            int ch2 = ich ^ swz(r2);
            size_t g2 = (size_t)36864 + (size_t)(p * 96 + r2) * 192 + kb + ch2 * 8;
            gld16(B3 + 2048 + wave * 512, Wh + g2);
            gld16(B3 + 5120 + wave * 512, Wl + g2);
        }
    };

    // ---------------- GEMM1: X -> hidden(96), relu ----------------
    f32x4 acc1[6];
#pragma unroll
    for (int j = 0; j < 6; j++) acc1[j] = (f32x4){0.f, 0.f, 0.f, 0.f};

    g1issue(0, 0);
    __syncthreads();
#pragma unroll 2
    for (int kb = 0; kb < 192; kb += 32) {
        int cur = (kb >> 5) & 1;
        if (kb + 32 < 192) g1issue(kb + 32, cur ^ 1);
        const u16* SA = LDS + 13312 + cur * 10240;
        int arow = wave * 16 + ln;
        int asl = arow * 32 + ((qd ^ swz(arow)) << 3);
        bf16x8 ah = *(const bf16x8*)&SA[asl];
        bf16x8 al = *(const bf16x8*)&SA[2048 + asl];
#pragma unroll
        for (int j = 0; j < 6; j++) {
            int brow = j * 16 + ln;
            int bsl = brow * 32 + ((qd ^ swz(brow)) << 3);
            bf16x8 bh = *(const bf16x8*)&SA[4096 + bsl];
            bf16x8 bl = *(const bf16x8*)&SA[7168 + bsl];
            acc1[j] = __builtin_amdgcn_mfma_f32_16x16x32_bf16(ah, bh, acc1[j], 0, 0, 0);
            acc1[j] = __builtin_amdgcn_mfma_f32_16x16x32_bf16(ah, bl, acc1[j], 0, 0, 0);
            acc1[j] = __builtin_amdgcn_mfma_f32_16x16x32_bf16(al, bh, acc1[j], 0, 0, 0);
        }
        __syncthreads();
    }

    g2issue(0, 0);              // hide W2 step-0 latency under the H-write
#pragma unroll
    for (int j = 0; j < 6; j++) {
        int o = j * 16 + ln;
        float bvf = Bias[o];                                   // b1off = 0
#pragma unroll
        for (int r = 0; r < 4; r++) {
            float v = fmaxf(acc1[j][r] + bvf, 0.f);            // relu
            u16 h, l; fsplit(v, h, l);
            int row = wave * 16 + qd * 4 + r;
            Hh[row * 104 + o] = h;
            Hl[row * 104 + o] = l;
        }
    }
    __syncthreads();

    // ---------------- GEMM2: hidden(LDS) -> y(192) ----------------
    f32x4 acc2[12];
#pragma unroll
    for (int j = 0; j < 12; j++) acc2[j] = (f32x4){0.f, 0.f, 0.f, 0.f};

#pragma unroll
    for (int kb = 0; kb < 96; kb += 32) {
        int cur = (kb >> 5) & 1;
        if (kb + 32 < 96) g2issue(kb + 32, cur ^ 1);
        const u16* B2 = LDS + 13312 + cur * 12288;
        bf16x8 ah = *(const bf16x8*)&Hh[(wave * 16 + ln) * 104 + kb + qd * 8];
        bf16x8 al = *(const bf16x8*)&Hl[(wave * 16 + ln) * 104 + kb + qd * 8];
#pragma unroll
        for (int j = 0; j < 12; j++) {
            int brow = j * 16 + ln;
            int bsl = brow * 32 + ((qd ^ swz(brow)) << 3);
            bf16x8 bh = *(const bf16x8*)&B2[bsl];
            bf16x8 bl = *(const bf16x8*)&B2[6144 + bsl];
            acc2[j] = __builtin_amdgcn_mfma_f32_16x16x32_bf16(ah, bh, acc2[j], 0, 0, 0);
            acc2[j] = __builtin_amdgcn_mfma_f32_16x16x32_bf16(ah, bl, acc2[j], 0, 0, 0);
            acc2[j] = __builtin_amdgcn_mfma_f32_16x16x32_bf16(al, bh, acc2[j], 0, 0, 0);
        }
        __syncthreads();
    }

    g3issue(0, 0);              // hide W3 step-0 latency under the epilogue

    // --------- epilogue: Xf' = relu((x+y)*bn_s+bn_t); global + LDS ---------
    u16* X2h = LDS;             // 64*192, byte-XOR swizzled (R2 scheme)
    u16* X2l = LDS + 12288;
#pragma unroll
    for (int j = 0; j < 12; j++) {
        int o = j * 16 + ln;
        float bvf = Bias[96 + o];                              // b2off = 96
#pragma unroll
        for (int r = 0; r < 4; r++) {
            int row  = wave * 16 + qd * 4 + r;
            int prow = p0 + row;
            float v = acc2[j][r] + bvf;
            size_t oidx = ((size_t)(img * M + prow)) * 192 + o;
            float xo = b2f(Xh[oidx]) + b2f(Xl[oidx]);
            v = fmaxf((xo + v) * Bias[1344 + o] + Bias[1536 + o], 0.f);
            u16 h, l; fsplit(v, h, l);
            if constexpr (WRITE_X) { Xh[oidx] = h; Xl[oidx] = l; }
            int off = ((row * 192 + o) * 2) ^ ((row & 7) << 4);
            *(u16*)((char*)X2h + off) = h;
            *(u16*)((char*)X2l + off) = l;
        }
    }
    __syncthreads();

    // ---- GEMM3: Xf'(LDS) -> Q|V, 4 passes x 96 outputs, dbuf W3 ----
    const int arow = wave * 16 + ln;
#pragma unroll 1
    for (int pass = 0; pass < 4; pass++) {
        f32x4 acc3[6];
#pragma unroll
        for (int j = 0; j < 6; j++) acc3[j] = (f32x4){0.f, 0.f, 0.f, 0.f};

#pragma unroll 2
        for (int t6 = 0; t6 < 6; t6++) {
            int s = pass * 6 + t6;
            int cur = t6 & 1;               // 6*pass is even -> s&1 == t6&1
            if (s < 23) g3issue(s + 1, cur ^ 1);
            int kb = t6 * 32;
            int aoff = ((arow * 192 + kb + qd * 8) * 2) ^ ((arow & 7) << 4);
            bf16x8 ah = *(const bf16x8*)((const char*)X2h + aoff);
            bf16x8 al = *(const bf16x8*)((const char*)X2l + aoff);
            const u16* B3 = LDS + 24576 + cur * 6144;
#pragma unroll
            for (int j = 0; j < 6; j++) {
                int brow = j * 16 + ln;
                int bsl = brow * 32 + ((qd ^ swz(brow)) << 3);
                bf16x8 bh = *(const bf16x8*)&B3[bsl];
                bf16x8 bl = *(const bf16x8*)&B3[3072 + bsl];
                acc3[j] = __builtin_amdgcn_mfma_f32_16x16x32_bf16(ah, bh, acc3[j], 0, 0, 0);
                acc3[j] = __builtin_amdgcn_mfma_f32_16x16x32_bf16(ah, bl, acc3[j], 0, 0, 0);
                acc3[j] = __builtin_amdgcn_mfma_f32_16x16x32_bf16(al, bh, acc3[j], 0, 0, 0);
            }
            __syncthreads();
        }
#pragma unroll
        for (int j = 0; j < 6; j++) {
            int o = pass * 96 + j * 16 + ln;
            float bvf = Bias[288 + o];                         // bqv
#pragma unroll
            for (int r = 0; r < 4; r++) {
                int prow = p0 + wave * 16 + qd * 4 + r;
                float v = acc3[j][r] + bvf;
                u16 q = f2h(v);
                size_t pb = ((size_t)(img * M + prow)) * 192;
                if (o < 192) Qf[pb + o] = q;
                else         Vf[pb + o - 192] = q;
            }
        }
    }
}

// ---------------------------------------------------------------------------
// Attention: wave per pixel, lane = channel (64).  kk = l*3+j.
// ---------------------------------------------------------------------------
__global__ void attn_kernel(const u16* __restrict__ Qb, const u16* __restrict__ Vb,
                            const u16* __restrict__ Keys,
                            u16* __restrict__ Rh, u16* __restrict__ Rl)
{
    const int lane = threadIdx.x & 63;
    const int wv   = threadIdx.x >> 6;
    const int p = blockIdx.x * 4 + wv;
    const int b = blockIdx.y;

    float qv[15], vv[15];
#pragma unroll
    for (int l = 0; l < 5; l++) {
        size_t base = ((size_t)((l * 4 + b) * 9216 + p)) * 192;
#pragma unroll
        for (int j = 0; j < 3; j++) {
            qv[l * 3 + j] = h2f(Qb[base + j * 64 + lane]);
            vv[l * 3 + j] = h2f(Vb[base + j * 64 + lane]);
        }
    }
    size_t kb = ((size_t)(b * 9216 + p)) * 192;
#pragma unroll
    for (int i = 0; i < 3; i++) {
        float kf = h2f(Keys[kb + i * 64 + lane]);
        float lg[15];
#pragma unroll
        for (int t = 0; t < 15; t++) {
            float s = kf * qv[t];
#pragma unroll
            for (int m = 1; m < 64; m <<= 1) s += __shfl_xor(s, m, 64);
            lg[t] = s;
        }
        float mx = lg[0];
#pragma unroll
        for (int t = 1; t < 15; t++) mx = fmaxf(mx, lg[t]);
        float sum = 0.f;
#pragma unroll
        for (int t = 0; t < 15; t++) { lg[t] = __expf(lg[t] - mx); sum += lg[t]; }
        float inv = 1.f / sum;
        float ref = 0.f;
#pragma unroll
        for (int t = 0; t < 15; t++) ref += lg[t] * vv[t];
        u16 h, lo; fsplit(ref * inv, h, lo);
        Rh[kb + i * 64 + lane] = h;
        Rl[kb + i * 64 + lane] = lo;
    }
}

// Final: split pixel-major La -> channel-major f32 out[b][c][p], LDS-tiled.
__launch_bounds__(256)
__global__ void transpose_out(const u16* __restrict__ Lah, const u16* __restrict__ Lal,
                              float* __restrict__ out)
{
    __shared__ float t[32][33];
    const int b  = blockIdx.z;
    const int c0 = blockIdx.y * 32;
    const int p0 = blockIdx.x * 32;
    const int tid = threadIdx.x;
#pragma unroll
    for (int it = 0; it < 4; it++) {
        int i = it * 256 + tid;
        int cl = i & 31, pl = i >> 5;
        size_t idx = ((size_t)(b * 9216 + p0 + pl)) * 192 + c0 + cl;
        t[pl][cl] = b2f(Lah[idx]) + b2f(Lal[idx]);
    }
    __syncthreads();
#pragma unroll
    for (int it = 0; it < 4; it++) {
        int i = it * 256 + tid;
        int pl = i & 31, cl = i >> 5;
        out[((size_t)(b * 192 + c0 + cl)) * 9216 + p0 + pl] = t[pl][cl];
    }
}

__global__ void ws_too_small_kernel(float* out)
{
    int gid = blockIdx.x * 256 + threadIdx.x;
    out[gid] = 12345.0f;
}

// ---------------------------------------------------------------------------
extern "C" void kernel_launch(void* const* d_in, const int* in_sizes, int n_in,
                              void* d_out, int out_size, void* d_ws, size_t ws_size,
                              hipStream_t stream)
{
    u16* ws = (u16*)d_ws;
    // u16-element offsets (16B aligned)
    const size_t oXh   = 0;            // 35,389,440
    const size_t oXl   = 35389440;
    const size_t oQ    = 70778880;     // f16, aliased by P0
    const size_t oV    = 106168320;    // f16, P0 tail
    const size_t oLah  = 141557760;    // aliased by P2
    const size_t oLal  = 148635648;    // aliased by P3
    const size_t oKeys = 155713536;    // f16, aliased by P4
    const size_t oRh   = 162791424;
    const size_t oRl   = 169869312;
    const size_t oWh   = 176947200;    // 368,640
    const size_t oWl   = 177315840;    // 368,640
    const size_t oBias = 177684480;    // 1728 f32 = 3456 u16
    const size_t oWtab = 177687936;    // 1536 f32 = 3072
    const size_t oJtab = 177691008;    // 1536 i32 = 3072
    const size_t oFlag = 177694080;    // 16
    const size_t need_bytes = (size_t)177694096 * 2;   // ~355 MB

    if (ws_size < need_bytes) {
        ws_too_small_kernel<<<dim3(out_size / 256), dim3(256), 0, stream>>>((float*)d_out);
        return;
    }

    u16* Xh   = ws + oXh;
    u16* Xl   = ws + oXl;
    u16* Qf   = ws + oQ;
    u16* Vf   = ws + oV;
    u16* Lah  = ws + oLah;
    u16* Lal  = ws + oLal;
    u16* Keys = ws + oKeys;
    u16* Rh   = ws + oRh;
    u16* Rl   = ws + oRl;
    u16* Wh   = ws + oWh;
    u16* Wl   = ws + oWl;
    float* Bias = (float*)(ws + oBias);
    float* wtab = (float*)(ws + oWtab);
    int*   jtab = (int*)(ws + oJtab);
    int*   flag = (int*)(ws + oFlag);

    // staging aliases (consumed by upsample2 before host regions are written)
    u32* P0 = (u32*)(ws + oQ);      // 4*36864*192 u32 = 56.6M u16 < Q+V region
    u32* P2 = (u32*)(ws + oLah);
    u32* P3 = (u32*)(ws + oLal);
    u32* P4 = (u32*)(ws + oKeys);

    SrcPtrs S;
    S.wk1 = d_in[5];  S.bk1 = d_in[6];
    S.wk2 = d_in[7];  S.bk2 = d_in[8];
    S.wk3 = d_in[9];  S.bk3 = d_in[10];
    S.wq  = d_in[11]; S.bq  = d_in[12];
    S.wv  = d_in[13]; S.bv  = d_in[14];
    S.wcf = d_in[15]; S.bcf = d_in[16];
    S.we1 = d_in[17]; S.be1 = d_in[18];
    S.we2 = d_in[19]; S.be2 = d_in[20];
    S.wr1 = d_in[21]; S.br1 = d_in[22];
    S.wr2 = d_in[23]; S.br2 = d_in[24];
    S.bns = d_in[25]; S.bnt = d_in[26];

    dim3 blk(256);
    detect_dtype<<<dim3(1), dim3(64), 0, stream>>>((const u16*)d_in[0], flag);
    pack_weights<<<dim3(1447), blk, 0, stream>>>(S, Wh, Wl, Bias, flag);
    build_tables<<<dim3(1), dim3(384), 0, stream>>>(wtab, jtab);

    transpose_in<0><<<dim3(1152, 6, 4), blk, 0, stream>>>(d_in[0], 36864, P0, nullptr, nullptr, flag);
    transpose_in<1><<<dim3( 288, 6, 4), blk, 0, stream>>>(d_in[1],  9216, nullptr, Xh, Xl, flag);
    transpose_in<0><<<dim3(  72, 6, 4), blk, 0, stream>>>(d_in[2],  2304, P2, nullptr, nullptr, flag);
    transpose_in<0><<<dim3(  18, 6, 4), blk, 0, stream>>>(d_in[3],   576, P3, nullptr, nullptr, flag);
    transpose_in<0><<<dim3(   5, 6, 4), blk, 0, stream>>>(d_in[4],   144, P4, nullptr, nullptr, flag);
    upsample2<4><<<dim3(6912,  4), blk, 0, stream>>>(P0, nullptr, nullptr, wtab, jtab, Xh, Xl);
    upsample2<2><<<dim3(6912, 12), blk, 0, stream>>>(P2, P3, P4, wtab, jtab, Xh, Xl);

    for (int k = 0; k < 5; k++) {
        // fused: residual block (in-place Xf RMW) + Q|V projection from LDS.
        // k==4: Xf is dead afterwards -> skip the global Xf write.
        if (k < 4)
            fused_res_qv<1><<<dim3(144, 1, 20), blk, 0, stream>>>(
                Xh, Xl, Wh, Wl, Bias, Qf, Vf);
        else
            fused_res_qv<0><<<dim3(144, 1, 20), blk, 0, stream>>>(
                Xh, Xl, Wh, Wl, Bias, Qf, Vf);
        if (k == 0) {
            // cat_fuse (K=960, relu) -> Refs; fused emb (+Keys) -> La, Keys
            conv_gemm<2, 12, 1, 2, 0><<<dim3(72, 1, 4), blk, 0, stream>>>(
                Xh, Xl, Wh, Wl, Bias, 110592, 672, 960, 192, Rh, Rl);
            fused_mlp<2, 0, 1><<<dim3(144, 1, 4), blk, 0, stream>>>(
                Rh, Rl, Wh, Wl, Bias, 294912, 864, 313344, 960, Lah, Lal, Keys);
        }
        // attention -> Refs (split); Keys came from the latest emb
        attn_kernel<<<dim3(2304, 4), blk, 0, stream>>>(Qf, Vf, Keys, Rh, Rl);
        // fused emb: Refs -> gelu-hidden(96) -> La (+Keys for next iter)
        if (k < 4)
            fused_mlp<2, 0, 1><<<dim3(144, 1, 4), blk, 0, stream>>>(
                Rh, Rl, Wh, Wl, Bias, 294912, 864, 313344, 960, Lah, Lal, Keys);
        else
            fused_mlp<2, 0, 0><<<dim3(144, 1, 4), blk, 0, stream>>>(
                Rh, Rl, Wh, Wl, Bias, 294912, 864, 313344, 960, Lah, Lal, nullptr);
    }
    transpose_out<<<dim3(288, 6, 4), blk, 0, stream>>>(Lah, Lal, (float*)d_out);
}

// Round 8
// 2456.474 us; speedup vs baseline: 1.0605x; 1.0605x over previous
//
#include <hip/hip_runtime.h>
#include <math.h>

typedef unsigned short u16;
typedef unsigned int   u32;
typedef __bf16 bf16x8 __attribute__((ext_vector_type(8)));
typedef float  f32x4  __attribute__((ext_vector_type(4)));

__device__ __forceinline__ float b2f(u16 u) {
    unsigned v = ((unsigned)u) << 16;
    return __uint_as_float(v);
}
__device__ __forceinline__ u16 f2b(float f) {
    unsigned x = __float_as_uint(f);
    unsigned r = (x + 0x7fffu + ((x >> 16) & 1u)) >> 16;  // RNE
    return (u16)r;
}
__device__ __forceinline__ void fsplit(float v, u16& h, u16& l) {
    h = f2b(v);
    l = f2b(v - b2f(h));
}
__device__ __forceinline__ float h2f(u16 u) {
    union { u16 us; _Float16 h; } c; c.us = u; return (float)c.h;
}
__device__ __forceinline__ u16 f2h(float f) {
    union { u16 us; _Float16 h; } c; c.h = (_Float16)f; return c.us;
}
__device__ __forceinline__ float ldx(const void* p, size_t i, int f32m) {
    return f32m ? ((const float*)p)[i] : b2f(((const u16*)p)[i]);
}

// Async 16B global->LDS DMA (no VGPR transit; tracked by vmcnt; drained by
// the implicit vmcnt(0) before s_barrier in __syncthreads).
__device__ __forceinline__ void gld16(u16* l, const u16* g) {
    __builtin_amdgcn_global_load_lds(
        (const __attribute__((address_space(1))) unsigned int*)g,
        (__attribute__((address_space(3))) unsigned int*)l,
        16, 0, 0);
}

// Bank swizzle for linear [row][32-u16] staging tiles (64B rows).
// Writer: thread t (chunk t = row*4+ch) loads global channel-quarter
// (t&3)^swz(row); reader fetches k-quarter qd at slot qd^swz(row).
// Gives 2-way (free) bank pattern on ds_read_b128; involution; global
// source stays coalesced (per-row permutation of 16B chunks only).
__device__ __forceinline__ int swz(int row) {
    return (row & 3) ^ ((row >> 2) & 3);
}

// flag[0] = input dtype (1=f32, 0=bf16).
__global__ void detect_dtype(const u16* __restrict__ x0, int* flag)
{
    int lane = threadIdx.x;  // 64 threads
    int bad = 0;
    for (int i = lane; i < 1024; i += 64) {
        float v = b2f(x0[i]);
        if (!(fabsf(v) < 32768.f)) bad = 1;
    }
    unsigned long long m = __ballot(bad);
    if (lane == 0) flag[0] = (m != 0ULL) ? 1 : 0;
}

// ---------------------------------------------------------------------------
// Pre-split ALL weights (hi/lo bf16 planes) + biases/bn (f32) into ws.
// Packed weight layout (elem offsets):
//   Wr1[96x192]@0  Wr2[192x96]@18432  Wqv[384x192]@36864  Wcf[192x960]@110592
//   We1[96x192]@294912  We2[192x96]@313344  Wk[192x192]@331776   (total 368640)
// Bias f32 layout: br1@0 br2@96 bqv@288 bcf@672 be1@864 be2@960 bk@1152
//   bns@1344 bnt@1536  (total 1728)
// ---------------------------------------------------------------------------
struct SrcPtrs {
    const void *wr1, *br1, *wr2, *br2, *wq, *bq, *wv, *bv, *wcf, *bcf;
    const void *we1, *be1, *we2, *be2, *wk1, *bk1, *wk2, *bk2, *wk3, *bk3;
    const void *bns, *bnt;
};
__global__ void pack_weights(SrcPtrs S, u16* __restrict__ Wh, u16* __restrict__ Wl,
                             float* __restrict__ Bias, const int* __restrict__ dflag)
{
    const int f32m = *dflag;
    int idx = blockIdx.x * 256 + threadIdx.x;
    if (idx < 368640) {
        const void* src; size_t si;
        if (idx < 18432)       { src = S.wr1; si = idx; }
        else if (idx < 36864)  { src = S.wr2; si = idx - 18432; }
        else if (idx < 110592) {
            int r = idx - 36864, o = r / 192, c = r % 192;
            if (o < 192) { src = S.wq; si = (size_t)o * 192 + c; }
            else         { src = S.wv; si = (size_t)(o - 192) * 192 + c; }
        }
        else if (idx < 294912) { src = S.wcf; si = idx - 110592; }
        else if (idx < 313344) { src = S.we1; si = idx - 294912; }
        else if (idx < 331776) { src = S.we2; si = idx - 313344; }
        else {
            int r = idx - 331776, o = r / 192, c = r % 192;
            src = (o < 64) ? S.wk1 : ((o < 128) ? S.wk2 : S.wk3);
            si = (size_t)(o & 63) * 192 + c;
        }
        u16 h, l; fsplit(ldx(src, si, f32m), h, l);
        Wh[idx] = h; Wl[idx] = l;
    } else if (idx < 370368) {
        int b = idx - 368640; const void* src; size_t si;
        if (b < 96)        { src = S.br1; si = b; }
        else if (b < 288)  { src = S.br2; si = b - 96; }
        else if (b < 672)  { int r = b - 288;
                             if (r < 192) { src = S.bq; si = r; }
                             else         { src = S.bv; si = r - 192; } }
        else if (b < 864)  { src = S.bcf; si = b - 672; }
        else if (b < 960)  { src = S.be1; si = b - 864; }
        else if (b < 1152) { src = S.be2; si = b - 960; }
        else if (b < 1344) { int r = b - 1152;
                             src = (r < 64) ? S.bk1 : ((r < 128) ? S.bk2 : S.bk3);
                             si = r & 63; }
        else if (b < 1536) { src = S.bns; si = b - 1344; }
        else               { src = S.bnt; si = b - 1536; }
        Bias[b] = ldx(src, si, f32m);
    }
}

// ---------------------------------------------------------------------------
// 1D resize tap tables per level {0,2,3,4}: 96 outputs x <=4 taps, weights
// pre-normalized (renorm folded in).  jax.image.resize triangle kernel.
// ---------------------------------------------------------------------------
__global__ void build_tables(float* __restrict__ wtab, int* __restrict__ jtab)
{
    int t = threadIdx.x;            // 384 = 4 levels x 96 outputs
    if (t >= 384) return;
    int li = t / 96, o = t % 96;
    const int ins[4] = {192, 48, 24, 12};
    int in = ins[li];
    float scale = (float)in / 96.0f;
    float ksc = fmaxf(scale, 1.0f);
    float cc = (o + 0.5f) * scale - 0.5f;
    float w[4] = {0.f, 0.f, 0.f, 0.f};
    int   j[4] = {0, 0, 0, 0};
    int n = 0; float s = 0.f;
    int jl = (int)floorf(cc - ksc), jh = (int)floorf(cc + ksc) + 1;
    for (int jj = jl; jj <= jh; jj++) {
        if (jj < 0 || jj >= in) continue;
        float ww = 1.0f - fabsf((float)jj - cc) / ksc;
        if (ww <= 0.f) continue;
        if (n < 4) { w[n] = ww; j[n] = jj; s += ww; n++; }
    }
    for (int i = 0; i < 4; i++) {
        wtab[li * 384 + o * 4 + i] = w[i] / s;
        jtab[li * 384 + o * 4 + i] = j[i];
    }
}

// ---------------------------------------------------------------------------
// LDS-tiled transpose of one level: channel-major [b][192][HW] -> pixel-major.
// ---------------------------------------------------------------------------
template<int SPLIT>
__launch_bounds__(256)
__global__ void transpose_in(const void* __restrict__ src, int HW,
                             u32* __restrict__ P, u16* __restrict__ Xh,
                             u16* __restrict__ Xl, const int* __restrict__ dflag)
{
    __shared__ float t[32][33];
    const int f32m = *dflag;
    const int b  = blockIdx.z;
    const int c0 = blockIdx.y * 32;
    const int p0 = blockIdx.x * 32;
    const int tid = threadIdx.x;
#pragma unroll
    for (int it = 0; it < 4; it++) {
        int i = it * 256 + tid;
        int pl = i & 31, cl = i >> 5;
        int p = p0 + pl;
        float v = 0.f;
        if (p < HW) v = ldx(src, ((size_t)(b * 192 + c0 + cl)) * HW + p, f32m);
        t[pl][cl] = v;
    }
    __syncthreads();
#pragma unroll
    for (int it = 0; it < 4; it++) {
        int i = it * 256 + tid;
        int cl = i & 31, pl = i >> 5;
        int p = p0 + pl;
        if (p >= HW) continue;
        float v = t[pl][cl];
        u16 h, l; fsplit(v, h, l);
        if constexpr (SPLIT) {
            size_t oi = ((size_t)((4 + b) * 9216 + p)) * 192 + c0 + cl;
            Xh[oi] = h; Xl[oi] = l;
        } else {
            P[((size_t)b * HW + p) * 192 + c0 + cl] = (u32)h | ((u32)l << 16);
        }
    }
}

// ---------------------------------------------------------------------------
// Table-driven bilinear resize.  TAPS=4: level 0.  TAPS=2: levels 2,3,4.
// ---------------------------------------------------------------------------
template<int TAPS>
__launch_bounds__(256)
__global__ void upsample2(const u32* __restrict__ Pa, const u32* __restrict__ Pb,
                          const u32* __restrict__ Pc,
                          const float* __restrict__ wtab, const int* __restrict__ jtab,
                          u16* __restrict__ Xh, u16* __restrict__ Xl)
{
    int li, b, l, in;
    const u32* P;
    if constexpr (TAPS == 4) {
        li = 0; b = blockIdx.y; l = 0; in = 192; P = Pa;
    } else {
        int yi = blockIdx.y;               // 12 = 3 levels x 4 batch
        li = 1 + (yi >> 2); b = yi & 3;
        const int lvl[4] = {0, 2, 3, 4};
        const int ins[4] = {192, 48, 24, 12};
        l = lvl[li]; in = ins[li];
        P = (li == 1) ? Pa : ((li == 2) ? Pb : Pc);
    }
    int gid = blockIdx.x * 256 + threadIdx.x;   // 9216*192
    int c = gid % 192;
    int p = gid / 192;
    int y = p / 96, x = p % 96;
    const float* wt = wtab + li * 384;
    const int*   jt = jtab + li * 384;

    size_t ib = (size_t)b * in * in * 192 + c;
    float a = 0.f;
#pragma unroll
    for (int iy = 0; iy < TAPS; iy++) {
        float wy = wt[y * 4 + iy];
        size_t rb = ib + (size_t)(jt[y * 4 + iy] * in) * 192;
        float ax = 0.f;
#pragma unroll
        for (int ix = 0; ix < TAPS; ix++) {
            u32 u = P[rb + jt[x * 4 + ix] * 192];
            ax += wt[x * 4 + ix] * (b2f((u16)u) + b2f((u16)(u >> 16)));
        }
        a += wy * ax;
    }
    size_t oi = ((size_t)(l * 4 + b) * 9216 + p) * 192 + c;
    u16 h, lo; fsplit(a, h, lo);
    Xh[oi] = h; Xl[oi] = lo;
}

// ---------------------------------------------------------------------------
// Split-precision conv1x1 GEMM (cat_fuse + keys), async-DMA edition.
// BM=64, BN=NT*16=192.  Double-buffered gload_lds staging (A + W), linear
// [row][32] tiles with swz() involution, ONE barrier per K-step.  Fragment
// values / kb order / hh-hl-lh MFMA sequence unchanged -> bit-identical.
// LDS: per buffer Ah@0(2048) Al@2048 Bh@4096(6144) Bl@10240; buf c at
// c*16384.  Total 32768 u16 = 65536 B -> 2 blocks/CU.
// ---------------------------------------------------------------------------
template<int NT, int ACT, int MODE, int OUT>
__launch_bounds__(256)
__global__ void conv_gemm(const u16* __restrict__ Ah, const u16* __restrict__ Al,
                          const u16* __restrict__ Wh, const u16* __restrict__ Wl,
                          const float* __restrict__ Bias,
                          int woff, int boff, int K, int O,
                          u16* __restrict__ out0, u16* __restrict__ out1)
{
    __shared__ __align__(16) u16 LDS[32768];

    const int tid  = threadIdx.x;
    const int lane = tid & 63, wave = tid >> 6;
    const int qd   = lane >> 4, ln = lane & 15;
    const int p0   = blockIdx.x * 64;
    const int img  = blockIdx.z;
    const int M    = 9216;
    const int irow = tid >> 2, ich = tid & 3;

    auto issue = [&](int kb, int c) {
        u16* S = LDS + c * 16384;
        {
            int ch = ich ^ swz(irow);
            size_t ga;
            if constexpr (MODE == 2) {
                int l = kb / 192;
                ga = ((size_t)((l * 4 + img) * M + p0 + irow)) * 192 + (kb - l * 192) + ch * 8;
            } else {
                ga = ((size_t)(img * M + p0 + irow)) * (size_t)K + kb + ch * 8;
            }
            gld16(S + wave * 512,        Ah + ga);
            gld16(S + 2048 + wave * 512, Al + ga);
        }
#pragma unroll
        for (int i = 0; i < 3; i++) {
            int idx = i * 256 + tid;
            int brow = idx >> 2;
            int bc = (idx & 3) ^ swz(brow);
            size_t gb = (size_t)woff + (size_t)brow * K + kb + bc * 8;
            gld16(S + 4096 + i * 2048 + wave * 512,  Wh + gb);
            gld16(S + 10240 + i * 2048 + wave * 512, Wl + gb);
        }
    };

    f32x4 acc[NT];
#pragma unroll
    for (int j = 0; j < NT; j++) acc[j] = (f32x4){0.f, 0.f, 0.f, 0.f};

    issue(0, 0);
    __syncthreads();
    for (int kb = 0; kb < K; kb += 32) {
        int cur = (kb >> 5) & 1;
        if (kb + 32 < K) issue(kb + 32, cur ^ 1);
        const u16* S = LDS + cur * 16384;
        int arow = wave * 16 + ln;
        int asl = arow * 32 + ((qd ^ swz(arow)) << 3);
        bf16x8 ah = *(const bf16x8*)&S[asl];
        bf16x8 al = *(const bf16x8*)&S[2048 + asl];
#pragma unroll
        for (int j = 0; j < NT; j++) {
            int brow = j * 16 + ln;
            int bsl = brow * 32 + ((qd ^ swz(brow)) << 3);
            bf16x8 bh = *(const bf16x8*)&S[4096 + bsl];
            bf16x8 bl = *(const bf16x8*)&S[10240 + bsl];
            acc[j] = __builtin_amdgcn_mfma_f32_16x16x32_bf16(ah, bh, acc[j], 0, 0, 0);
            acc[j] = __builtin_amdgcn_mfma_f32_16x16x32_bf16(ah, bl, acc[j], 0, 0, 0);
            acc[j] = __builtin_amdgcn_mfma_f32_16x16x32_bf16(al, bh, acc[j], 0, 0, 0);
        }
        __syncthreads();
    }

#pragma unroll
    for (int j = 0; j < NT; j++) {
        int o = j * 16 + ln;
        float bvf = Bias[boff + o];
#pragma unroll
        for (int r = 0; r < 4; r++) {
            int prow = p0 + wave * 16 + qd * 4 + r;
            float v = acc[j][r] + bvf;
            if constexpr (ACT == 1) v = fmaxf(v, 0.f);
            if constexpr (OUT == 0) {
                size_t oidx = ((size_t)(img * M + prow)) * (size_t)O + o;
                u16 h, l; fsplit(v, h, l);
                out0[oidx] = h; out1[oidx] = l;
            } else if constexpr (OUT == 1) {
                out0[((size_t)(img * M + prow)) * (size_t)O + o] = f2h(v);
            } else {
                size_t pb = ((size_t)(img * M + prow)) * 192;
                if (o < 192) out0[pb + o] = f2h(v);
                else         out1[pb + o - 192] = f2h(v);
            }
        }
    }
}

// ---------------------------------------------------------------------------
// Fused 192 -> 96(ACT1) -> 192 MLP (emb), async-DMA staging edition (R6).
// LDS map (u16): Hh@0 Hl@6656 | G1 SA[c]@13312+c*10240
//   (Ah 0..2048, Al 2048.., Bh 4096.., Bl 7168..) | G2 B2[c]@13312+c*12288
//   (Wh 0..6144, Wl 6144..).  Total 38912 u16 = 77824 B -> 2 blocks/CU.
// ---------------------------------------------------------------------------
template<int ACT1, int MODE2>
__launch_bounds__(256)
__global__ void fused_mlp(const u16* __restrict__ Ah, const u16* __restrict__ Al,
                          const u16* __restrict__ Wh, const u16* __restrict__ Wl,
                          const float* __restrict__ Bias,
                          int w1off, int b1off, int w2off, int b2off,
                          u16* __restrict__ outh, u16* __restrict__ outl)
{
    __shared__ __align__(16) u16 LDS[38912];
    u16* Hh = LDS;              // 64*104
    u16* Hl = LDS + 6656;

    const int tid  = threadIdx.x;
    const int lane = tid & 63, wave = tid >> 6;
    const int qd   = lane >> 4, ln = lane & 15;
    const int p0   = blockIdx.x * 64;
    const int img  = blockIdx.z;
    const int M    = 9216;
    const int irow = tid >> 2, ich = tid & 3;

    auto g1issue = [&](int kb, int c) {
        u16* SA = LDS + 13312 + c * 10240;
        int ch = ich ^ swz(irow);
        size_t ga = ((size_t)(img * M + p0 + irow)) * 192 + kb + ch * 8;
        gld16(SA + wave * 512,        Ah + ga);
        gld16(SA + 2048 + wave * 512, Al + ga);
        size_t gb = (size_t)w1off + (size_t)irow * 192 + kb + ch * 8;
        gld16(SA + 4096 + wave * 512, Wh + gb);
        gld16(SA + 7168 + wave * 512, Wl + gb);
        if (tid < 128) {
            int r2 = 64 + irow;
            int ch2 = ich ^ swz(r2);
            size_t gb2 = (size_t)w1off + (size_t)r2 * 192 + kb + ch2 * 8;
            gld16(SA + 6144 + wave * 512, Wh + gb2);
            gld16(SA + 9216 + wave * 512, Wl + gb2);
        }
    };
    auto g2issue = [&](int kb, int c) {
        u16* B2 = LDS + 13312 + c * 12288;
#pragma unroll
        for (int i = 0; i < 3; i++) {
            int r = i * 64 + irow;
            int ch = ich ^ swz(r);
            size_t g = (size_t)w2off + (size_t)r * 96 + kb + ch * 8;
            gld16(B2 + i * 2048 + wave * 512,        Wh + g);
            gld16(B2 + 6144 + i * 2048 + wave * 512, Wl + g);
        }
    };

    // ---------------- GEMM1: A -> hidden(96), ACT1 ----------------
    f32x4 acc1[6];
#pragma unroll
    for (int j = 0; j < 6; j++) acc1[j] = (f32x4){0.f, 0.f, 0.f, 0.f};

    g1issue(0, 0);
    __syncthreads();
#pragma unroll 2
    for (int kb = 0; kb < 192; kb += 32) {
        int cur = (kb >> 5) & 1;
        if (kb + 32 < 192) g1issue(kb + 32, cur ^ 1);
        const u16* SA = LDS + 13312 + cur * 10240;
        int arow = wave * 16 + ln;
        int asl = arow * 32 + ((qd ^ swz(arow)) << 3);
        bf16x8 ah = *(const bf16x8*)&SA[asl];
        bf16x8 al = *(const bf16x8*)&SA[2048 + asl];
#pragma unroll
        for (int j = 0; j < 6; j++) {
            int brow = j * 16 + ln;
            int bsl = brow * 32 + ((qd ^ swz(brow)) << 3);
            bf16x8 bh = *(const bf16x8*)&SA[4096 + bsl];
            bf16x8 bl = *(const bf16x8*)&SA[7168 + bsl];
            acc1[j] = __builtin_amdgcn_mfma_f32_16x16x32_bf16(ah, bh, acc1[j], 0, 0, 0);
            acc1[j] = __builtin_amdgcn_mfma_f32_16x16x32_bf16(ah, bl, acc1[j], 0, 0, 0);
            acc1[j] = __builtin_amdgcn_mfma_f32_16x16x32_bf16(al, bh, acc1[j], 0, 0, 0);
        }
        __syncthreads();
    }

    g2issue(0, 0);              // hide W2 step-0 latency under the H-write
#pragma unroll
    for (int j = 0; j < 6; j++) {
        int o = j * 16 + ln;
        float bvf = Bias[b1off + o];
#pragma unroll
        for (int r = 0; r < 4; r++) {
            float v = acc1[j][r] + bvf;
            if constexpr (ACT1 == 1) v = fmaxf(v, 0.f);
            if constexpr (ACT1 == 2) v = 0.5f * v * (1.f + erff(v * 0.70710678118654752f));
            u16 h, l; fsplit(v, h, l);
            int row = wave * 16 + qd * 4 + r;
            Hh[row * 104 + o] = h;
            Hl[row * 104 + o] = l;
        }
    }
    __syncthreads();

    // ---------------- GEMM2: hidden(LDS) -> out(192) ----------------
    f32x4 acc2[12];
#pragma unroll
    for (int j = 0; j < 12; j++) acc2[j] = (f32x4){0.f, 0.f, 0.f, 0.f};

#pragma unroll
    for (int kb = 0; kb < 96; kb += 32) {
        int cur = (kb >> 5) & 1;
        if (kb + 32 < 96) g2issue(kb + 32, cur ^ 1);
        const u16* B2 = LDS + 13312 + cur * 12288;
        bf16x8 ah = *(const bf16x8*)&Hh[(wave * 16 + ln) * 104 + kb + qd * 8];
        bf16x8 al = *(const bf16x8*)&Hl[(wave * 16 + ln) * 104 + kb + qd * 8];
#pragma unroll
        for (int j = 0; j < 12; j++) {
            int brow = j * 16 + ln;
            int bsl = brow * 32 + ((qd ^ swz(brow)) << 3);
            bf16x8 bh = *(const bf16x8*)&B2[bsl];
            bf16x8 bl = *(const bf16x8*)&B2[6144 + bsl];
            acc2[j] = __builtin_amdgcn_mfma_f32_16x16x32_bf16(ah, bh, acc2[j], 0, 0, 0);
            acc2[j] = __builtin_amdgcn_mfma_f32_16x16x32_bf16(ah, bl, acc2[j], 0, 0, 0);
            acc2[j] = __builtin_amdgcn_mfma_f32_16x16x32_bf16(al, bh, acc2[j], 0, 0, 0);
        }
        __syncthreads();
    }

#pragma unroll
    for (int j = 0; j < 12; j++) {
        int o = j * 16 + ln;
        float bvf = Bias[b2off + o];
#pragma unroll
        for (int r = 0; r < 4; r++) {
            int prow = p0 + wave * 16 + qd * 4 + r;
            float v = acc2[j][r] + bvf;
            size_t oidx = ((size_t)(img * M + prow)) * 192 + o;
            if constexpr (MODE2 == 1) {
                float xo = b2f(outh[oidx]) + b2f(outl[oidx]);
                v = fmaxf((xo + v) * Bias[1344 + o] + Bias[1536 + o], 0.f);
            }
            u16 h, l; fsplit(v, h, l);
            outh[oidx] = h; outl[oidx] = l;
        }
    }
}

// ---------------------------------------------------------------------------
// FUSED residual-MLP + QV projection, async-DMA staging edition (R6, proven).
// ---------------------------------------------------------------------------
template<int WRITE_X>
__launch_bounds__(256)
__global__ void fused_res_qv(u16* __restrict__ Xh, u16* __restrict__ Xl,
                             const u16* __restrict__ Wh, const u16* __restrict__ Wl,
                             const float* __restrict__ Bias,
                             u16* __restrict__ Qf, u16* __restrict__ Vf)
{
    __shared__ __align__(16) u16 LDS[38912];
    u16* Hh = LDS;              // 64*104
    u16* Hl = LDS + 6656;

    const int tid  = threadIdx.x;
    const int lane = tid & 63, wave = tid >> 6;
    const int qd   = lane >> 4, ln = lane & 15;
    const int p0   = blockIdx.x * 64;
    const int img  = blockIdx.z;
    const int M    = 9216;
    const int irow = tid >> 2, ich = tid & 3;

    auto g1issue = [&](int kb, int c) {
        u16* SA = LDS + 13312 + c * 10240;
        int ch = ich ^ swz(irow);
        size_t ga = ((size_t)(img * M + p0 + irow)) * 192 + kb + ch * 8;
        gld16(SA + wave * 512,        Xh + ga);
        gld16(SA + 2048 + wave * 512, Xl + ga);
        size_t gb = (size_t)irow * 192 + kb + ch * 8;          // w1off = 0
        gld16(SA + 4096 + wave * 512, Wh + gb);
        gld16(SA + 7168 + wave * 512, Wl + gb);
        if (tid < 128) {
            int r2 = 64 + irow;
            int ch2 = ich ^ swz(r2);
            size_t gb2 = (size_t)r2 * 192 + kb + ch2 * 8;
            gld16(SA + 6144 + wave * 512, Wh + gb2);
            gld16(SA + 9216 + wave * 512, Wl + gb2);
        }
    };
    auto g2issue = [&](int kb, int c) {
        u16* B2 = LDS + 13312 + c * 12288;
#pragma unroll
        for (int i = 0; i < 3; i++) {
            int r = i * 64 + irow;
            int ch = ich ^ swz(r);
            size_t g = (size_t)18432 + (size_t)r * 96 + kb + ch * 8;   // w2off
            gld16(B2 + i * 2048 + wave * 512,        Wh + g);
            gld16(B2 + 6144 + i * 2048 + wave * 512, Wl + g);
        }
    };
    auto g3issue = [&](int s, int c) {          // s = pass*6 + t, 0..23
        int p = s / 6, kb = (s - p * 6) * 32;
        u16* B3 = LDS + 24576 + c * 6144;
        int ch = ich ^ swz(irow);
        size_t g = (size_t)36864 + (size_t)(p * 96 + irow) * 192 + kb + ch * 8;
        gld16(B3 + wave * 512,        Wh + g);
        gld16(B3 + 3072 + wave * 512, Wl + g);
        if (tid < 128) {
            int r2 = 64 + irow;
            int ch2 = ich ^ swz(r2);
            size_t g2 = (size_t)36864 + (size_t)(p * 96 + r2) * 192 + kb + ch2 * 8;
            gld16(B3 + 2048 + wave * 512, Wh + g2);
            gld16(B3 + 5120 + wave * 512, Wl + g2);
        }
    };

    // ---------------- GEMM1: X -> hidden(96), relu ----------------
    f32x4 acc1[6];
#pragma unroll
    for (int j = 0; j < 6; j++) acc1[j] = (f32x4){0.f, 0.f, 0.f, 0.f};

    g1issue(0, 0);
    __syncthreads();
#pragma unroll 2
    for (int kb = 0; kb < 192; kb += 32) {
        int cur = (kb >> 5) & 1;
        if (kb + 32 < 192) g1issue(kb + 32, cur ^ 1);
        const u16* SA = LDS + 13312 + cur * 10240;
        int arow = wave * 16 + ln;
        int asl = arow * 32 + ((qd ^ swz(arow)) << 3);
        bf16x8 ah = *(const bf16x8*)&SA[asl];
        bf16x8 al = *(const bf16x8*)&SA[2048 + asl];
#pragma unroll
        for (int j = 0; j < 6; j++) {
            int brow = j * 16 + ln;
            int bsl = brow * 32 + ((qd ^ swz(brow)) << 3);
            bf16x8 bh = *(const bf16x8*)&SA[4096 + bsl];
            bf16x8 bl = *(const bf16x8*)&SA[7168 + bsl];
            acc1[j] = __builtin_amdgcn_mfma_f32_16x16x32_bf16(ah, bh, acc1[j], 0, 0, 0);
            acc1[j] = __builtin_amdgcn_mfma_f32_16x16x32_bf16(ah, bl, acc1[j], 0, 0, 0);
            acc1[j] = __builtin_amdgcn_mfma_f32_16x16x32_bf16(al, bh, acc1[j], 0, 0, 0);
        }
        __syncthreads();
    }

    g2issue(0, 0);              // hide W2 step-0 latency under the H-write
#pragma unroll
    for (int j = 0; j < 6; j++) {
        int o = j * 16 + ln;
        float bvf = Bias[o];                                   // b1off = 0
#pragma unroll
        for (int r = 0; r < 4; r++) {
            float v = fmaxf(acc1[j][r] + bvf, 0.f);            // relu
            u16 h, l; fsplit(v, h, l);
            int row = wave * 16 + qd * 4 + r;
            Hh[row * 104 + o] = h;
            Hl[row * 104 + o] = l;
        }
    }
    __syncthreads();

    // ---------------- GEMM2: hidden(LDS) -> y(192) ----------------
    f32x4 acc2[12];
#pragma unroll
    for (int j = 0; j < 12; j++) acc2[j] = (f32x4){0.f, 0.f, 0.f, 0.f};

#pragma unroll
    for (int kb = 0; kb < 96; kb += 32) {
        int cur = (kb >> 5) & 1;
        if (kb + 32 < 96) g2issue(kb + 32, cur ^ 1);
        const u16* B2 = LDS + 13312 + cur * 12288;
        bf16x8 ah = *(const bf16x8*)&Hh[(wave * 16 + ln) * 104 + kb + qd * 8];
        bf16x8 al = *(const bf16x8*)&Hl[(wave * 16 + ln) * 104 + kb + qd * 8];
#pragma unroll
        for (int j = 0; j < 12; j++) {
            int brow = j * 16 + ln;
            int bsl = brow * 32 + ((qd ^ swz(brow)) << 3);
            bf16x8 bh = *(const bf16x8*)&B2[bsl];
            bf16x8 bl = *(const bf16x8*)&B2[6144 + bsl];
            acc2[j] = __builtin_amdgcn_mfma_f32_16x16x32_bf16(ah, bh, acc2[j], 0, 0, 0);
            acc2[j] = __builtin_amdgcn_mfma_f32_16x16x32_bf16(ah, bl, acc2[j], 0, 0, 0);
            acc2[j] = __builtin_amdgcn_mfma_f32_16x16x32_bf16(al, bh, acc2[j], 0, 0, 0);
        }
        __syncthreads();
    }

    g3issue(0, 0);              // hide W3 step-0 latency under the epilogue

    // --------- epilogue: Xf' = relu((x+y)*bn_s+bn_t); global + LDS ---------
    u16* X2h = LDS;             // 64*192, byte-XOR swizzled (R2 scheme)
    u16* X2l = LDS + 12288;
#pragma unroll
    for (int j = 0; j < 12; j++) {
        int o = j * 16 + ln;
        float bvf = Bias[96 + o];                              // b2off = 96
#pragma unroll
        for (int r = 0; r < 4; r++) {
            int row  = wave * 16 + qd * 4 + r;
            int prow = p0 + row;
            float v = acc2[j][r] + bvf;
            size_t oidx = ((size_t)(img * M + prow)) * 192 + o;
            float xo = b2f(Xh[oidx]) + b2f(Xl[oidx]);
            v = fmaxf((xo + v) * Bias[1344 + o] + Bias[1536 + o], 0.f);
            u16 h, l; fsplit(v, h, l);
            if constexpr (WRITE_X) { Xh[oidx] = h; Xl[oidx] = l; }
            int off = ((row * 192 + o) * 2) ^ ((row & 7) << 4);
            *(u16*)((char*)X2h + off) = h;
            *(u16*)((char*)X2l + off) = l;
        }
    }
    __syncthreads();

    // ---- GEMM3: Xf'(LDS) -> Q|V, 4 passes x 96 outputs, dbuf W3 ----
    const int arow = wave * 16 + ln;
#pragma unroll 1
    for (int pass = 0; pass < 4; pass++) {
        f32x4 acc3[6];
#pragma unroll
        for (int j = 0; j < 6; j++) acc3[j] = (f32x4){0.f, 0.f, 0.f, 0.f};

#pragma unroll 2
        for (int t6 = 0; t6 < 6; t6++) {
            int s = pass * 6 + t6;
            int cur = t6 & 1;               // 6*pass is even -> s&1 == t6&1
            if (s < 23) g3issue(s + 1, cur ^ 1);
            int kb = t6 * 32;
            int aoff = ((arow * 192 + kb + qd * 8) * 2) ^ ((arow & 7) << 4);
            bf16x8 ah = *(const bf16x8*)((const char*)X2h + aoff);
            bf16x8 al = *(const bf16x8*)((const char*)X2l + aoff);
            const u16* B3 = LDS + 24576 + cur * 6144;
#pragma unroll
            for (int j = 0; j < 6; j++) {
                int brow = j * 16 + ln;
                int bsl = brow * 32 + ((qd ^ swz(brow)) << 3);
                bf16x8 bh = *(const bf16x8*)&B3[bsl];
                bf16x8 bl = *(const bf16x8*)&B3[3072 + bsl];
                acc3[j] = __builtin_amdgcn_mfma_f32_16x16x32_bf16(ah, bh, acc3[j], 0, 0, 0);
                acc3[j] = __builtin_amdgcn_mfma_f32_16x16x32_bf16(ah, bl, acc3[j], 0, 0, 0);
                acc3[j] = __builtin_amdgcn_mfma_f32_16x16x32_bf16(al, bh, acc3[j], 0, 0, 0);
            }
            __syncthreads();
        }
#pragma unroll
        for (int j = 0; j < 6; j++) {
            int o = pass * 96 + j * 16 + ln;
            float bvf = Bias[288 + o];                         // bqv
#pragma unroll
            for (int r = 0; r < 4; r++) {
                int prow = p0 + wave * 16 + qd * 4 + r;
                float v = acc3[j][r] + bvf;
                u16 q = f2h(v);
                size_t pb = ((size_t)(img * M + prow)) * 192;
                if (o < 192) Qf[pb + o] = q;
                else         Vf[pb + o - 192] = q;
            }
        }
    }
}

// ---------------------------------------------------------------------------
// Attention: wave per pixel, lane = channel (64).  kk = l*3+j.
// ---------------------------------------------------------------------------
__global__ void attn_kernel(const u16* __restrict__ Qb, const u16* __restrict__ Vb,
                            const u16* __restrict__ Keys,
                            u16* __restrict__ Rh, u16* __restrict__ Rl)
{
    const int lane = threadIdx.x & 63;
    const int wv   = threadIdx.x >> 6;
    const int p = blockIdx.x * 4 + wv;
    const int b = blockIdx.y;

    float qv[15], vv[15];
#pragma unroll
    for (int l = 0; l < 5; l++) {
        size_t base = ((size_t)((l * 4 + b) * 9216 + p)) * 192;
#pragma unroll
        for (int j = 0; j < 3; j++) {
            qv[l * 3 + j] = h2f(Qb[base + j * 64 + lane]);
            vv[l * 3 + j] = h2f(Vb[base + j * 64 + lane]);
        }
    }
    size_t kb = ((size_t)(b * 9216 + p)) * 192;
#pragma unroll
    for (int i = 0; i < 3; i++) {
        float kf = h2f(Keys[kb + i * 64 + lane]);
        float lg[15];
#pragma unroll
        for (int t = 0; t < 15; t++) {
            float s = kf * qv[t];
#pragma unroll
            for (int m = 1; m < 64; m <<= 1) s += __shfl_xor(s, m, 64);
            lg[t] = s;
        }
        float mx = lg[0];
#pragma unroll
        for (int t = 1; t < 15; t++) mx = fmaxf(mx, lg[t]);
        float sum = 0.f;
#pragma unroll
        for (int t = 0; t < 15; t++) { lg[t] = __expf(lg[t] - mx); sum += lg[t]; }
        float inv = 1.f / sum;
        float ref = 0.f;
#pragma unroll
        for (int t = 0; t < 15; t++) ref += lg[t] * vv[t];
        u16 h, lo; fsplit(ref * inv, h, lo);
        Rh[kb + i * 64 + lane] = h;
        Rl[kb + i * 64 + lane] = lo;
    }
}

// Final: split pixel-major La -> channel-major f32 out[b][c][p], LDS-tiled.
__launch_bounds__(256)
__global__ void transpose_out(const u16* __restrict__ Lah, const u16* __restrict__ Lal,
                              float* __restrict__ out)
{
    __shared__ float t[32][33];
    const int b  = blockIdx.z;
    const int c0 = blockIdx.y * 32;
    const int p0 = blockIdx.x * 32;
    const int tid = threadIdx.x;
#pragma unroll
    for (int it = 0; it < 4; it++) {
        int i = it * 256 + tid;
        int cl = i & 31, pl = i >> 5;
        size_t idx = ((size_t)(b * 9216 + p0 + pl)) * 192 + c0 + cl;
        t[pl][cl] = b2f(Lah[idx]) + b2f(Lal[idx]);
    }
    __syncthreads();
#pragma unroll
    for (int it = 0; it < 4; it++) {
        int i = it * 256 + tid;
        int pl = i & 31, cl = i >> 5;
        out[((size_t)(b * 192 + c0 + cl)) * 9216 + p0 + pl] = t[pl][cl];
    }
}

__global__ void ws_too_small_kernel(float* out)
{
    int gid = blockIdx.x * 256 + threadIdx.x;
    out[gid] = 12345.0f;
}

// ---------------------------------------------------------------------------
extern "C" void kernel_launch(void* const* d_in, const int* in_sizes, int n_in,
                              void* d_out, int out_size, void* d_ws, size_t ws_size,
                              hipStream_t stream)
{
    u16* ws = (u16*)d_ws;
    // u16-element offsets (16B aligned)
    const size_t oXh   = 0;            // 35,389,440
    const size_t oXl   = 35389440;
    const size_t oQ    = 70778880;     // f16, aliased by P0
    const size_t oV    = 106168320;    // f16, P0 tail
    const size_t oLah  = 141557760;    // aliased by P2
    const size_t oLal  = 148635648;    // aliased by P3
    const size_t oKeys = 155713536;    // f16, aliased by P4
    const size_t oRh   = 162791424;
    const size_t oRl   = 169869312;
    const size_t oWh   = 176947200;    // 368,640
    const size_t oWl   = 177315840;    // 368,640
    const size_t oBias = 177684480;    // 1728 f32 = 3456 u16
    const size_t oWtab = 177687936;    // 1536 f32 = 3072
    const size_t oJtab = 177691008;    // 1536 i32 = 3072
    const size_t oFlag = 177694080;    // 16
    const size_t need_bytes = (size_t)177694096 * 2;   // ~355 MB

    if (ws_size < need_bytes) {
        ws_too_small_kernel<<<dim3(out_size / 256), dim3(256), 0, stream>>>((float*)d_out);
        return;
    }

    u16* Xh   = ws + oXh;
    u16* Xl   = ws + oXl;
    u16* Qf   = ws + oQ;
    u16* Vf   = ws + oV;
    u16* Lah  = ws + oLah;
    u16* Lal  = ws + oLal;
    u16* Keys = ws + oKeys;
    u16* Rh   = ws + oRh;
    u16* Rl   = ws + oRl;
    u16* Wh   = ws + oWh;
    u16* Wl   = ws + oWl;
    float* Bias = (float*)(ws + oBias);
    float* wtab = (float*)(ws + oWtab);
    int*   jtab = (int*)(ws + oJtab);
    int*   flag = (int*)(ws + oFlag);

    // staging aliases (consumed by upsample2 before host regions are written)
    u32* P0 = (u32*)(ws + oQ);      // 4*36864*192 u32 = 56.6M u16 < Q+V region
    u32* P2 = (u32*)(ws + oLah);
    u32* P3 = (u32*)(ws + oLal);
    u32* P4 = (u32*)(ws + oKeys);

    SrcPtrs S;
    S.wk1 = d_in[5];  S.bk1 = d_in[6];
    S.wk2 = d_in[7];  S.bk2 = d_in[8];
    S.wk3 = d_in[9];  S.bk3 = d_in[10];
    S.wq  = d_in[11]; S.bq  = d_in[12];
    S.wv  = d_in[13]; S.bv  = d_in[14];
    S.wcf = d_in[15]; S.bcf = d_in[16];
    S.we1 = d_in[17]; S.be1 = d_in[18];
    S.we2 = d_in[19]; S.be2 = d_in[20];
    S.wr1 = d_in[21]; S.br1 = d_in[22];
    S.wr2 = d_in[23]; S.br2 = d_in[24];
    S.bns = d_in[25]; S.bnt = d_in[26];

    dim3 blk(256);
    detect_dtype<<<dim3(1), dim3(64), 0, stream>>>((const u16*)d_in[0], flag);
    pack_weights<<<dim3(1447), blk, 0, stream>>>(S, Wh, Wl, Bias, flag);
    build_tables<<<dim3(1), dim3(384), 0, stream>>>(wtab, jtab);

    transpose_in<0><<<dim3(1152, 6, 4), blk, 0, stream>>>(d_in[0], 36864, P0, nullptr, nullptr, flag);
    transpose_in<1><<<dim3( 288, 6, 4), blk, 0, stream>>>(d_in[1],  9216, nullptr, Xh, Xl, flag);
    transpose_in<0><<<dim3(  72, 6, 4), blk, 0, stream>>>(d_in[2],  2304, P2, nullptr, nullptr, flag);
    transpose_in<0><<<dim3(  18, 6, 4), blk, 0, stream>>>(d_in[3],   576, P3, nullptr, nullptr, flag);
    transpose_in<0><<<dim3(   5, 6, 4), blk, 0, stream>>>(d_in[4],   144, P4, nullptr, nullptr, flag);
    upsample2<4><<<dim3(6912,  4), blk, 0, stream>>>(P0, nullptr, nullptr, wtab, jtab, Xh, Xl);
    upsample2<2><<<dim3(6912, 12), blk, 0, stream>>>(P2, P3, P4, wtab, jtab, Xh, Xl);

    for (int k = 0; k < 5; k++) {
        // fused: residual block (in-place Xf RMW) + Q|V projection from LDS.
        // k==4: Xf is dead afterwards -> skip the global Xf write.
        if (k < 4)
            fused_res_qv<1><<<dim3(144, 1, 20), blk, 0, stream>>>(
                Xh, Xl, Wh, Wl, Bias, Qf, Vf);
        else
            fused_res_qv<0><<<dim3(144, 1, 20), blk, 0, stream>>>(
                Xh, Xl, Wh, Wl, Bias, Qf, Vf);
        if (k == 0) {
            // cat_fuse (K=960, relu) -> Refs; fused emb -> La
            conv_gemm<12, 1, 2, 0><<<dim3(144, 1, 4), blk, 0, stream>>>(
                Xh, Xl, Wh, Wl, Bias, 110592, 672, 960, 192, Rh, Rl);
            fused_mlp<2, 0><<<dim3(144, 1, 4), blk, 0, stream>>>(
                Rh, Rl, Wh, Wl, Bias, 294912, 864, 313344, 960, Lah, Lal);
        }
        // keys: La -> Keys (f16, 3 projections packed)
        conv_gemm<12, 0, 0, 1><<<dim3(144, 1, 4), blk, 0, stream>>>(
            Lah, Lal, Wh, Wl, Bias, 331776, 1152, 192, 192, Keys, nullptr);
        // attention -> Refs (split)
        attn_kernel<<<dim3(2304, 4), blk, 0, stream>>>(Qf, Vf, Keys, Rh, Rl);
        // fused emb: Refs -> gelu-hidden(96) -> La
        fused_mlp<2, 0><<<dim3(144, 1, 4), blk, 0, stream>>>(
            Rh, Rl, Wh, Wl, Bias, 294912, 864, 313344, 960, Lah, Lal);
    }
    transpose_out<<<dim3(288, 6, 4), blk, 0, stream>>>(Lah, Lal, (float*)d_out);
}

// Round 9
// 2265.527 us; speedup vs baseline: 1.1498x; 1.0843x over previous
//
#include <hip/hip_runtime.h>
#include <math.h>

typedef unsigned short u16;
typedef unsigned int   u32;
typedef __bf16 bf16x8 __attribute__((ext_vector_type(8)));
typedef float  f32x4  __attribute__((ext_vector_type(4)));

__device__ __forceinline__ float b2f(u16 u) {
    unsigned v = ((unsigned)u) << 16;
    return __uint_as_float(v);
}
__device__ __forceinline__ u16 f2b(float f) {
    unsigned x = __float_as_uint(f);
    unsigned r = (x + 0x7fffu + ((x >> 16) & 1u)) >> 16;  // RNE
    return (u16)r;
}
__device__ __forceinline__ void fsplit(float v, u16& h, u16& l) {
    h = f2b(v);
    l = f2b(v - b2f(h));
}
__device__ __forceinline__ float h2f(u16 u) {
    union { u16 us; _Float16 h; } c; c.us = u; return (float)c.h;
}
__device__ __forceinline__ u16 f2h(float f) {
    union { u16 us; _Float16 h; } c; c.h = (_Float16)f; return c.us;
}
__device__ __forceinline__ float ldx(const void* p, size_t i, int f32m) {
    return f32m ? ((const float*)p)[i] : b2f(((const u16*)p)[i]);
}

// Async 16B global->LDS DMA (no VGPR transit; tracked by vmcnt; drained by
// the implicit vmcnt(0) before s_barrier in __syncthreads).
__device__ __forceinline__ void gld16(u16* l, const u16* g) {
    __builtin_amdgcn_global_load_lds(
        (const __attribute__((address_space(1))) unsigned int*)g,
        (__attribute__((address_space(3))) unsigned int*)l,
        16, 0, 0);
}

// Bank swizzle for linear [row][32-u16] staging tiles (64B rows).
// Writer: thread t (chunk t = row*4+ch) loads global channel-quarter
// (t&3)^swz(row); reader fetches k-quarter qd at slot qd^swz(row).
__device__ __forceinline__ int swz(int row) {
    return (row & 3) ^ ((row >> 2) & 3);
}

// flag[0] = input dtype (1=f32, 0=bf16).
__global__ void detect_dtype(const u16* __restrict__ x0, int* flag)
{
    int lane = threadIdx.x;  // 64 threads
    int bad = 0;
    for (int i = lane; i < 1024; i += 64) {
        float v = b2f(x0[i]);
        if (!(fabsf(v) < 32768.f)) bad = 1;
    }
    unsigned long long m = __ballot(bad);
    if (lane == 0) flag[0] = (m != 0ULL) ? 1 : 0;
}

// ---------------------------------------------------------------------------
// Pre-split ALL weights (hi/lo bf16 planes) + biases/bn (f32) into ws.
// Packed weight layout (elem offsets):
//   Wr1[96x192]@0  Wr2[192x96]@18432  Wqv[384x192]@36864  Wcf[192x960]@110592
//   We1[96x192]@294912  We2[192x96]@313344  Wk[192x192]@331776   (total 368640)
// Bias f32 layout: br1@0 br2@96 bqv@288 bcf@672 be1@864 be2@960 bk@1152
//   bns@1344 bnt@1536  (total 1728)
// ---------------------------------------------------------------------------
struct SrcPtrs {
    const void *wr1, *br1, *wr2, *br2, *wq, *bq, *wv, *bv, *wcf, *bcf;
    const void *we1, *be1, *we2, *be2, *wk1, *bk1, *wk2, *bk2, *wk3, *bk3;
    const void *bns, *bnt;
};
__global__ void pack_weights(SrcPtrs S, u16* __restrict__ Wh, u16* __restrict__ Wl,
                             float* __restrict__ Bias, const int* __restrict__ dflag)
{
    const int f32m = *dflag;
    int idx = blockIdx.x * 256 + threadIdx.x;
    if (idx < 368640) {
        const void* src; size_t si;
        if (idx < 18432)       { src = S.wr1; si = idx; }
        else if (idx < 36864)  { src = S.wr2; si = idx - 18432; }
        else if (idx < 110592) {
            int r = idx - 36864, o = r / 192, c = r % 192;
            if (o < 192) { src = S.wq; si = (size_t)o * 192 + c; }
            else         { src = S.wv; si = (size_t)(o - 192) * 192 + c; }
        }
        else if (idx < 294912) { src = S.wcf; si = idx - 110592; }
        else if (idx < 313344) { src = S.we1; si = idx - 294912; }
        else if (idx < 331776) { src = S.we2; si = idx - 313344; }
        else {
            int r = idx - 331776, o = r / 192, c = r % 192;
            src = (o < 64) ? S.wk1 : ((o < 128) ? S.wk2 : S.wk3);
            si = (size_t)(o & 63) * 192 + c;
        }
        u16 h, l; fsplit(ldx(src, si, f32m), h, l);
        Wh[idx] = h; Wl[idx] = l;
    } else if (idx < 370368) {
        int b = idx - 368640; const void* src; size_t si;
        if (b < 96)        { src = S.br1; si = b; }
        else if (b < 288)  { src = S.br2; si = b - 96; }
        else if (b < 672)  { int r = b - 288;
                             if (r < 192) { src = S.bq; si = r; }
                             else         { src = S.bv; si = r - 192; } }
        else if (b < 864)  { src = S.bcf; si = b - 672; }
        else if (b < 960)  { src = S.be1; si = b - 864; }
        else if (b < 1152) { src = S.be2; si = b - 960; }
        else if (b < 1344) { int r = b - 1152;
                             src = (r < 64) ? S.bk1 : ((r < 128) ? S.bk2 : S.bk3);
                             si = r & 63; }
        else if (b < 1536) { src = S.bns; si = b - 1344; }
        else               { src = S.bnt; si = b - 1536; }
        Bias[b] = ldx(src, si, f32m);
    }
}

// ---------------------------------------------------------------------------
// 1D resize tap tables per level {0,2,3,4}: 96 outputs x <=4 taps.
// ---------------------------------------------------------------------------
__global__ void build_tables(float* __restrict__ wtab, int* __restrict__ jtab)
{
    int t = threadIdx.x;            // 384 = 4 levels x 96 outputs
    if (t >= 384) return;
    int li = t / 96, o = t % 96;
    const int ins[4] = {192, 48, 24, 12};
    int in = ins[li];
    float scale = (float)in / 96.0f;
    float ksc = fmaxf(scale, 1.0f);
    float cc = (o + 0.5f) * scale - 0.5f;
    float w[4] = {0.f, 0.f, 0.f, 0.f};
    int   j[4] = {0, 0, 0, 0};
    int n = 0; float s = 0.f;
    int jl = (int)floorf(cc - ksc), jh = (int)floorf(cc + ksc) + 1;
    for (int jj = jl; jj <= jh; jj++) {
        if (jj < 0 || jj >= in) continue;
        float ww = 1.0f - fabsf((float)jj - cc) / ksc;
        if (ww <= 0.f) continue;
        if (n < 4) { w[n] = ww; j[n] = jj; s += ww; n++; }
    }
    for (int i = 0; i < 4; i++) {
        wtab[li * 384 + o * 4 + i] = w[i] / s;
        jtab[li * 384 + o * 4 + i] = j[i];
    }
}

// ---------------------------------------------------------------------------
// LDS-tiled transpose of one level: channel-major [b][192][HW] -> pixel-major.
// ---------------------------------------------------------------------------
template<int SPLIT>
__launch_bounds__(256)
__global__ void transpose_in(const void* __restrict__ src, int HW,
                             u32* __restrict__ P, u16* __restrict__ Xh,
                             u16* __restrict__ Xl, const int* __restrict__ dflag)
{
    __shared__ float t[32][33];
    const int f32m = *dflag;
    const int b  = blockIdx.z;
    const int c0 = blockIdx.y * 32;
    const int p0 = blockIdx.x * 32;
    const int tid = threadIdx.x;
#pragma unroll
    for (int it = 0; it < 4; it++) {
        int i = it * 256 + tid;
        int pl = i & 31, cl = i >> 5;
        int p = p0 + pl;
        float v = 0.f;
        if (p < HW) v = ldx(src, ((size_t)(b * 192 + c0 + cl)) * HW + p, f32m);
        t[pl][cl] = v;
    }
    __syncthreads();
#pragma unroll
    for (int it = 0; it < 4; it++) {
        int i = it * 256 + tid;
        int cl = i & 31, pl = i >> 5;
        int p = p0 + pl;
        if (p >= HW) continue;
        float v = t[pl][cl];
        u16 h, l; fsplit(v, h, l);
        if constexpr (SPLIT) {
            size_t oi = ((size_t)((4 + b) * 9216 + p)) * 192 + c0 + cl;
            Xh[oi] = h; Xl[oi] = l;
        } else {
            P[((size_t)b * HW + p) * 192 + c0 + cl] = (u32)h | ((u32)l << 16);
        }
    }
}

// ---------------------------------------------------------------------------
// Table-driven bilinear resize.  TAPS=4: level 0.  TAPS=2: levels 2,3,4.
// ---------------------------------------------------------------------------
template<int TAPS>
__launch_bounds__(256)
__global__ void upsample2(const u32* __restrict__ Pa, const u32* __restrict__ Pb,
                          const u32* __restrict__ Pc,
                          const float* __restrict__ wtab, const int* __restrict__ jtab,
                          u16* __restrict__ Xh, u16* __restrict__ Xl)
{
    int li, b, l, in;
    const u32* P;
    if constexpr (TAPS == 4) {
        li = 0; b = blockIdx.y; l = 0; in = 192; P = Pa;
    } else {
        int yi = blockIdx.y;               // 12 = 3 levels x 4 batch
        li = 1 + (yi >> 2); b = yi & 3;
        const int lvl[4] = {0, 2, 3, 4};
        const int ins[4] = {192, 48, 24, 12};
        l = lvl[li]; in = ins[li];
        P = (li == 1) ? Pa : ((li == 2) ? Pb : Pc);
    }
    int gid = blockIdx.x * 256 + threadIdx.x;   // 9216*192
    int c = gid % 192;
    int p = gid / 192;
    int y = p / 96, x = p % 96;
    const float* wt = wtab + li * 384;
    const int*   jt = jtab + li * 384;

    size_t ib = (size_t)b * in * in * 192 + c;
    float a = 0.f;
#pragma unroll
    for (int iy = 0; iy < TAPS; iy++) {
        float wy = wt[y * 4 + iy];
        size_t rb = ib + (size_t)(jt[y * 4 + iy] * in) * 192;
        float ax = 0.f;
#pragma unroll
        for (int ix = 0; ix < TAPS; ix++) {
            u32 u = P[rb + jt[x * 4 + ix] * 192];
            ax += wt[x * 4 + ix] * (b2f((u16)u) + b2f((u16)(u >> 16)));
        }
        a += wy * ax;
    }
    size_t oi = ((size_t)(l * 4 + b) * 9216 + p) * 192 + c;
    u16 h, lo; fsplit(a, h, lo);
    Xh[oi] = h; Xl[oi] = lo;
}

// ---------------------------------------------------------------------------
// Split-precision conv1x1 GEMM (cat_fuse + keys), async-DMA, 8-wave edition.
// 512 threads: wave = (wr = wave&3 row-group, wc = wave>>2 col-half); each
// wave computes NT/2 output-column fragments for its 16 rows.  DMA issue is
// gated to tid<256 (identical chunk mapping as the 256-thread version) ->
// bit-identical.  LDS 65536 B -> 2 blocks/CU = 16 waves/CU (4/SIMD).
// ---------------------------------------------------------------------------
template<int NT, int ACT, int MODE, int OUT>
__launch_bounds__(512, 4)
__global__ void conv_gemm(const u16* __restrict__ Ah, const u16* __restrict__ Al,
                          const u16* __restrict__ Wh, const u16* __restrict__ Wl,
                          const float* __restrict__ Bias,
                          int woff, int boff, int K, int O,
                          u16* __restrict__ out0, u16* __restrict__ out1)
{
    constexpr int NTW = NT / 2;
    __shared__ __align__(16) u16 LDS[32768];

    const int tid  = threadIdx.x;
    const int lane = tid & 63, wave = tid >> 6;
    const int wr   = wave & 3, wc = wave >> 2;
    const int qd   = lane >> 4, ln = lane & 15;
    const int p0   = blockIdx.x * 64;
    const int img  = blockIdx.z;
    const int M    = 9216;
    const int irow = tid >> 2, ich = tid & 3;

    auto issue = [&](int kb, int c) {
        if (tid >= 256) return;
        u16* S = LDS + c * 16384;
        {
            int ch = ich ^ swz(irow);
            size_t ga;
            if constexpr (MODE == 2) {
                int l = kb / 192;
                ga = ((size_t)((l * 4 + img) * M + p0 + irow)) * 192 + (kb - l * 192) + ch * 8;
            } else {
                ga = ((size_t)(img * M + p0 + irow)) * (size_t)K + kb + ch * 8;
            }
            gld16(S + wave * 512,        Ah + ga);
            gld16(S + 2048 + wave * 512, Al + ga);
        }
#pragma unroll
        for (int i = 0; i < 3; i++) {
            int idx = i * 256 + tid;
            int brow = idx >> 2;
            int bc = (idx & 3) ^ swz(brow);
            size_t gb = (size_t)woff + (size_t)brow * K + kb + bc * 8;
            gld16(S + 4096 + i * 2048 + wave * 512,  Wh + gb);
            gld16(S + 10240 + i * 2048 + wave * 512, Wl + gb);
        }
    };

    f32x4 acc[NTW];
#pragma unroll
    for (int j = 0; j < NTW; j++) acc[j] = (f32x4){0.f, 0.f, 0.f, 0.f};

    issue(0, 0);
    __syncthreads();
    for (int kb = 0; kb < K; kb += 32) {
        int cur = (kb >> 5) & 1;
        if (kb + 32 < K) issue(kb + 32, cur ^ 1);
        const u16* S = LDS + cur * 16384;
        int arow = wr * 16 + ln;
        int asl = arow * 32 + ((qd ^ swz(arow)) << 3);
        bf16x8 ah = *(const bf16x8*)&S[asl];
        bf16x8 al = *(const bf16x8*)&S[2048 + asl];
#pragma unroll
        for (int j = 0; j < NTW; j++) {
            int brow = (wc * NTW + j) * 16 + ln;
            int bsl = brow * 32 + ((qd ^ swz(brow)) << 3);
            bf16x8 bh = *(const bf16x8*)&S[4096 + bsl];
            bf16x8 bl = *(const bf16x8*)&S[10240 + bsl];
            acc[j] = __builtin_amdgcn_mfma_f32_16x16x32_bf16(ah, bh, acc[j], 0, 0, 0);
            acc[j] = __builtin_amdgcn_mfma_f32_16x16x32_bf16(ah, bl, acc[j], 0, 0, 0);
            acc[j] = __builtin_amdgcn_mfma_f32_16x16x32_bf16(al, bh, acc[j], 0, 0, 0);
        }
        __syncthreads();
    }

#pragma unroll
    for (int j = 0; j < NTW; j++) {
        int o = (wc * NTW + j) * 16 + ln;
        float bvf = Bias[boff + o];
#pragma unroll
        for (int r = 0; r < 4; r++) {
            int prow = p0 + wr * 16 + qd * 4 + r;
            float v = acc[j][r] + bvf;
            if constexpr (ACT == 1) v = fmaxf(v, 0.f);
            if constexpr (OUT == 0) {
                size_t oidx = ((size_t)(img * M + prow)) * (size_t)O + o;
                u16 h, l; fsplit(v, h, l);
                out0[oidx] = h; out1[oidx] = l;
            } else if constexpr (OUT == 1) {
                out0[((size_t)(img * M + prow)) * (size_t)O + o] = f2h(v);
            } else {
                size_t pb = ((size_t)(img * M + prow)) * 192;
                if (o < 192) out0[pb + o] = f2h(v);
                else         out1[pb + o - 192] = f2h(v);
            }
        }
    }
}

// ---------------------------------------------------------------------------
// Fused 192 -> 96(ACT1) -> 192 MLP (emb), async-DMA, 8-wave edition.
// Same LDS layout as the 256-thread version (77824 B -> 2 blocks/CU = 16
// waves/CU); waves split output columns (wc), DMA gated to tid<256.
// ---------------------------------------------------------------------------
template<int ACT1, int MODE2>
__launch_bounds__(512, 4)
__global__ void fused_mlp(const u16* __restrict__ Ah, const u16* __restrict__ Al,
                          const u16* __restrict__ Wh, const u16* __restrict__ Wl,
                          const float* __restrict__ Bias,
                          int w1off, int b1off, int w2off, int b2off,
                          u16* __restrict__ outh, u16* __restrict__ outl)
{
    __shared__ __align__(16) u16 LDS[38912];
    u16* Hh = LDS;              // 64*104
    u16* Hl = LDS + 6656;

    const int tid  = threadIdx.x;
    const int lane = tid & 63, wave = tid >> 6;
    const int wr   = wave & 3, wc = wave >> 2;
    const int qd   = lane >> 4, ln = lane & 15;
    const int p0   = blockIdx.x * 64;
    const int img  = blockIdx.z;
    const int M    = 9216;
    const int irow = tid >> 2, ich = tid & 3;

    auto g1issue = [&](int kb, int c) {
        if (tid >= 256) return;
        u16* SA = LDS + 13312 + c * 10240;
        int ch = ich ^ swz(irow);
        size_t ga = ((size_t)(img * M + p0 + irow)) * 192 + kb + ch * 8;
        gld16(SA + wave * 512,        Ah + ga);
        gld16(SA + 2048 + wave * 512, Al + ga);
        size_t gb = (size_t)w1off + (size_t)irow * 192 + kb + ch * 8;
        gld16(SA + 4096 + wave * 512, Wh + gb);
        gld16(SA + 7168 + wave * 512, Wl + gb);
        if (tid < 128) {
            int r2 = 64 + irow;
            int ch2 = ich ^ swz(r2);
            size_t gb2 = (size_t)w1off + (size_t)r2 * 192 + kb + ch2 * 8;
            gld16(SA + 6144 + wave * 512, Wh + gb2);
            gld16(SA + 9216 + wave * 512, Wl + gb2);
        }
    };
    auto g2issue = [&](int kb, int c) {
        if (tid >= 256) return;
        u16* B2 = LDS + 13312 + c * 12288;
#pragma unroll
        for (int i = 0; i < 3; i++) {
            int r = i * 64 + irow;
            int ch = ich ^ swz(r);
            size_t g = (size_t)w2off + (size_t)r * 96 + kb + ch * 8;
            gld16(B2 + i * 2048 + wave * 512,        Wh + g);
            gld16(B2 + 6144 + i * 2048 + wave * 512, Wl + g);
        }
    };

    // ---------------- GEMM1: A -> hidden(96), ACT1 ----------------
    f32x4 acc1[3];
#pragma unroll
    for (int j = 0; j < 3; j++) acc1[j] = (f32x4){0.f, 0.f, 0.f, 0.f};

    g1issue(0, 0);
    __syncthreads();
#pragma unroll 2
    for (int kb = 0; kb < 192; kb += 32) {
        int cur = (kb >> 5) & 1;
        if (kb + 32 < 192) g1issue(kb + 32, cur ^ 1);
        const u16* SA = LDS + 13312 + cur * 10240;
        int arow = wr * 16 + ln;
        int asl = arow * 32 + ((qd ^ swz(arow)) << 3);
        bf16x8 ah = *(const bf16x8*)&SA[asl];
        bf16x8 al = *(const bf16x8*)&SA[2048 + asl];
#pragma unroll
        for (int j = 0; j < 3; j++) {
            int brow = (wc * 3 + j) * 16 + ln;
            int bsl = brow * 32 + ((qd ^ swz(brow)) << 3);
            bf16x8 bh = *(const bf16x8*)&SA[4096 + bsl];
            bf16x8 bl = *(const bf16x8*)&SA[7168 + bsl];
            acc1[j] = __builtin_amdgcn_mfma_f32_16x16x32_bf16(ah, bh, acc1[j], 0, 0, 0);
            acc1[j] = __builtin_amdgcn_mfma_f32_16x16x32_bf16(ah, bl, acc1[j], 0, 0, 0);
            acc1[j] = __builtin_amdgcn_mfma_f32_16x16x32_bf16(al, bh, acc1[j], 0, 0, 0);
        }
        __syncthreads();
    }

    g2issue(0, 0);              // hide W2 step-0 latency under the H-write
#pragma unroll
    for (int j = 0; j < 3; j++) {
        int o = (wc * 3 + j) * 16 + ln;
        float bvf = Bias[b1off + o];
#pragma unroll
        for (int r = 0; r < 4; r++) {
            float v = acc1[j][r] + bvf;
            if constexpr (ACT1 == 1) v = fmaxf(v, 0.f);
            if constexpr (ACT1 == 2) v = 0.5f * v * (1.f + erff(v * 0.70710678118654752f));
            u16 h, l; fsplit(v, h, l);
            int row = wr * 16 + qd * 4 + r;
            Hh[row * 104 + o] = h;
            Hl[row * 104 + o] = l;
        }
    }
    __syncthreads();

    // ---------------- GEMM2: hidden(LDS) -> out(192) ----------------
    f32x4 acc2[6];
#pragma unroll
    for (int j = 0; j < 6; j++) acc2[j] = (f32x4){0.f, 0.f, 0.f, 0.f};

#pragma unroll
    for (int kb = 0; kb < 96; kb += 32) {
        int cur = (kb >> 5) & 1;
        if (kb + 32 < 96) g2issue(kb + 32, cur ^ 1);
        const u16* B2 = LDS + 13312 + cur * 12288;
        bf16x8 ah = *(const bf16x8*)&Hh[(wr * 16 + ln) * 104 + kb + qd * 8];
        bf16x8 al = *(const bf16x8*)&Hl[(wr * 16 + ln) * 104 + kb + qd * 8];
#pragma unroll
        for (int j = 0; j < 6; j++) {
            int brow = (wc * 6 + j) * 16 + ln;
            int bsl = brow * 32 + ((qd ^ swz(brow)) << 3);
            bf16x8 bh = *(const bf16x8*)&B2[bsl];
            bf16x8 bl = *(const bf16x8*)&B2[6144 + bsl];
            acc2[j] = __builtin_amdgcn_mfma_f32_16x16x32_bf16(ah, bh, acc2[j], 0, 0, 0);
            acc2[j] = __builtin_amdgcn_mfma_f32_16x16x32_bf16(ah, bl, acc2[j], 0, 0, 0);
            acc2[j] = __builtin_amdgcn_mfma_f32_16x16x32_bf16(al, bh, acc2[j], 0, 0, 0);
        }
        __syncthreads();
    }

#pragma unroll
    for (int j = 0; j < 6; j++) {
        int o = (wc * 6 + j) * 16 + ln;
        float bvf = Bias[b2off + o];
#pragma unroll
        for (int r = 0; r < 4; r++) {
            int prow = p0 + wr * 16 + qd * 4 + r;
            float v = acc2[j][r] + bvf;
            size_t oidx = ((size_t)(img * M + prow)) * 192 + o;
            if constexpr (MODE2 == 1) {
                float xo = b2f(outh[oidx]) + b2f(outl[oidx]);
                v = fmaxf((xo + v) * Bias[1344 + o] + Bias[1536 + o], 0.f);
            }
            u16 h, l; fsplit(v, h, l);
            outh[oidx] = h; outl[oidx] = l;
        }
    }
}

// ---------------------------------------------------------------------------
// FUSED residual-MLP + QV projection, async-DMA, 8-wave edition.
// Same LDS map as the 256-thread R6 version (77824 B -> 2 blocks/CU, now 16
// waves/CU = 4/SIMD).  Waves split output columns; DMA gated tid<256.
// Numerics bit-identical (fragments / kb order / hh-hl-lh sequence).
// ---------------------------------------------------------------------------
template<int WRITE_X>
__launch_bounds__(512, 4)
__global__ void fused_res_qv(u16* __restrict__ Xh, u16* __restrict__ Xl,
                             const u16* __restrict__ Wh, const u16* __restrict__ Wl,
                             const float* __restrict__ Bias,
                             u16* __restrict__ Qf, u16* __restrict__ Vf)
{
    __shared__ __align__(16) u16 LDS[38912];
    u16* Hh = LDS;              // 64*104
    u16* Hl = LDS + 6656;

    const int tid  = threadIdx.x;
    const int lane = tid & 63, wave = tid >> 6;
    const int wr   = wave & 3, wc = wave >> 2;
    const int qd   = lane >> 4, ln = lane & 15;
    const int p0   = blockIdx.x * 64;
    const int img  = blockIdx.z;
    const int M    = 9216;
    const int irow = tid >> 2, ich = tid & 3;

    auto g1issue = [&](int kb, int c) {
        if (tid >= 256) return;
        u16* SA = LDS + 13312 + c * 10240;
        int ch = ich ^ swz(irow);
        size_t ga = ((size_t)(img * M + p0 + irow)) * 192 + kb + ch * 8;
        gld16(SA + wave * 512,        Xh + ga);
        gld16(SA + 2048 + wave * 512, Xl + ga);
        size_t gb = (size_t)irow * 192 + kb + ch * 8;          // w1off = 0
        gld16(SA + 4096 + wave * 512, Wh + gb);
        gld16(SA + 7168 + wave * 512, Wl + gb);
        if (tid < 128) {
            int r2 = 64 + irow;
            int ch2 = ich ^ swz(r2);
            size_t gb2 = (size_t)r2 * 192 + kb + ch2 * 8;
            gld16(SA + 6144 + wave * 512, Wh + gb2);
            gld16(SA + 9216 + wave * 512, Wl + gb2);
        }
    };
    auto g2issue = [&](int kb, int c) {
        if (tid >= 256) return;
        u16* B2 = LDS + 13312 + c * 12288;
#pragma unroll
        for (int i = 0; i < 3; i++) {
            int r = i * 64 + irow;
            int ch = ich ^ swz(r);
            size_t g = (size_t)18432 + (size_t)r * 96 + kb + ch * 8;   // w2off
            gld16(B2 + i * 2048 + wave * 512,        Wh + g);
            gld16(B2 + 6144 + i * 2048 + wave * 512, Wl + g);
        }
    };
    auto g3issue = [&](int s, int c) {          // s = pass*6 + t, 0..23
        if (tid >= 256) return;
        int p = s / 6, kb = (s - p * 6) * 32;
        u16* B3 = LDS + 24576 + c * 6144;
        int ch = ich ^ swz(irow);
        size_t g = (size_t)36864 + (size_t)(p * 96 + irow) * 192 + kb + ch * 8;
        gld16(B3 + wave * 512,        Wh + g);
        gld16(B3 + 3072 + wave * 512, Wl + g);
        if (tid < 128) {
            int r2 = 64 + irow;
            int ch2 = ich ^ swz(r2);
            size_t g2 = (size_t)36864 + (size_t)(p * 96 + r2) * 192 + kb + ch2 * 8;
            gld16(B3 + 2048 + wave * 512, Wh + g2);
            gld16(B3 + 5120 + wave * 512, Wl + g2);
        }
    };

    // ---------------- GEMM1: X -> hidden(96), relu ----------------
    f32x4 acc1[3];
#pragma unroll
    for (int j = 0; j < 3; j++) acc1[j] = (f32x4){0.f, 0.f, 0.f, 0.f};

    g1issue(0, 0);
    __syncthreads();
#pragma unroll 2
    for (int kb = 0; kb < 192; kb += 32) {
        int cur = (kb >> 5) & 1;
        if (kb + 32 < 192) g1issue(kb + 32, cur ^ 1);
        const u16* SA = LDS + 13312 + cur * 10240;
        int arow = wr * 16 + ln;
        int asl = arow * 32 + ((qd ^ swz(arow)) << 3);
        bf16x8 ah = *(const bf16x8*)&SA[asl];
        bf16x8 al = *(const bf16x8*)&SA[2048 + asl];
#pragma unroll
        for (int j = 0; j < 3; j++) {
            int brow = (wc * 3 + j) * 16 + ln;
            int bsl = brow * 32 + ((qd ^ swz(brow)) << 3);
            bf16x8 bh = *(const bf16x8*)&SA[4096 + bsl];
            bf16x8 bl = *(const bf16x8*)&SA[7168 + bsl];
            acc1[j] = __builtin_amdgcn_mfma_f32_16x16x32_bf16(ah, bh, acc1[j], 0, 0, 0);
            acc1[j] = __builtin_amdgcn_mfma_f32_16x16x32_bf16(ah, bl, acc1[j], 0, 0, 0);
            acc1[j] = __builtin_amdgcn_mfma_f32_16x16x32_bf16(al, bh, acc1[j], 0, 0, 0);
        }
        __syncthreads();
    }

    g2issue(0, 0);              // hide W2 step-0 latency under the H-write
#pragma unroll
    for (int j = 0; j < 3; j++) {
        int o = (wc * 3 + j) * 16 + ln;
        float bvf = Bias[o];                                   // b1off = 0
#pragma unroll
        for (int r = 0; r < 4; r++) {
            float v = fmaxf(acc1[j][r] + bvf, 0.f);            // relu
            u16 h, l; fsplit(v, h, l);
            int row = wr * 16 + qd * 4 + r;
            Hh[row * 104 + o] = h;
            Hl[row * 104 + o] = l;
        }
    }
    __syncthreads();

    // ---------------- GEMM2: hidden(LDS) -> y(192) ----------------
    f32x4 acc2[6];
#pragma unroll
    for (int j = 0; j < 6; j++) acc2[j] = (f32x4){0.f, 0.f, 0.f, 0.f};

#pragma unroll
    for (int kb = 0; kb < 96; kb += 32) {
        int cur = (kb >> 5) & 1;
        if (kb + 32 < 96) g2issue(kb + 32, cur ^ 1);
        const u16* B2 = LDS + 13312 + cur * 12288;
        bf16x8 ah = *(const bf16x8*)&Hh[(wr * 16 + ln) * 104 + kb + qd * 8];
        bf16x8 al = *(const bf16x8*)&Hl[(wr * 16 + ln) * 104 + kb + qd * 8];
#pragma unroll
        for (int j = 0; j < 6; j++) {
            int brow = (wc * 6 + j) * 16 + ln;
            int bsl = brow * 32 + ((qd ^ swz(brow)) << 3);
            bf16x8 bh = *(const bf16x8*)&B2[bsl];
            bf16x8 bl = *(const bf16x8*)&B2[6144 + bsl];
            acc2[j] = __builtin_amdgcn_mfma_f32_16x16x32_bf16(ah, bh, acc2[j], 0, 0, 0);
            acc2[j] = __builtin_amdgcn_mfma_f32_16x16x32_bf16(ah, bl, acc2[j], 0, 0, 0);
            acc2[j] = __builtin_amdgcn_mfma_f32_16x16x32_bf16(al, bh, acc2[j], 0, 0, 0);
        }
        __syncthreads();
    }

    g3issue(0, 0);              // hide W3 step-0 latency under the epilogue

    // --------- epilogue: Xf' = relu((x+y)*bn_s+bn_t); global + LDS ---------
    u16* X2h = LDS;             // 64*192, byte-XOR swizzled (R2 scheme)
    u16* X2l = LDS + 12288;
#pragma unroll
    for (int j = 0; j < 6; j++) {
        int o = (wc * 6 + j) * 16 + ln;
        float bvf = Bias[96 + o];                              // b2off = 96
#pragma unroll
        for (int r = 0; r < 4; r++) {
            int row  = wr * 16 + qd * 4 + r;
            int prow = p0 + row;
            float v = acc2[j][r] + bvf;
            size_t oidx = ((size_t)(img * M + prow)) * 192 + o;
            float xo = b2f(Xh[oidx]) + b2f(Xl[oidx]);
            v = fmaxf((xo + v) * Bias[1344 + o] + Bias[1536 + o], 0.f);
            u16 h, l; fsplit(v, h, l);
            if constexpr (WRITE_X) { Xh[oidx] = h; Xl[oidx] = l; }
            int off = ((row * 192 + o) * 2) ^ ((row & 7) << 4);
            *(u16*)((char*)X2h + off) = h;
            *(u16*)((char*)X2l + off) = l;
        }
    }
    __syncthreads();

    // ---- GEMM3: Xf'(LDS) -> Q|V, 4 passes x 96 outputs, dbuf W3 ----
    const int arow = wr * 16 + ln;
#pragma unroll 1
    for (int pass = 0; pass < 4; pass++) {
        f32x4 acc3[3];
#pragma unroll
        for (int j = 0; j < 3; j++) acc3[j] = (f32x4){0.f, 0.f, 0.f, 0.f};

#pragma unroll 2
        for (int t6 = 0; t6 < 6; t6++) {
            int s = pass * 6 + t6;
            int cur = t6 & 1;               // 6*pass is even -> s&1 == t6&1
            if (s < 23) g3issue(s + 1, cur ^ 1);
            int kb = t6 * 32;
            int aoff = ((arow * 192 + kb + qd * 8) * 2) ^ ((arow & 7) << 4);
            bf16x8 ah = *(const bf16x8*)((const char*)X2h + aoff);
            bf16x8 al = *(const bf16x8*)((const char*)X2l + aoff);
            const u16* B3 = LDS + 24576 + cur * 6144;
#pragma unroll
            for (int j = 0; j < 3; j++) {
                int brow = (wc * 3 + j) * 16 + ln;
                int bsl = brow * 32 + ((qd ^ swz(brow)) << 3);
                bf16x8 bh = *(const bf16x8*)&B3[bsl];
                bf16x8 bl = *(const bf16x8*)&B3[3072 + bsl];
                acc3[j] = __builtin_amdgcn_mfma_f32_16x16x32_bf16(ah, bh, acc3[j], 0, 0, 0);
                acc3[j] = __builtin_amdgcn_mfma_f32_16x16x32_bf16(ah, bl, acc3[j], 0, 0, 0);
                acc3[j] = __builtin_amdgcn_mfma_f32_16x16x32_bf16(al, bh, acc3[j], 0, 0, 0);
            }
            __syncthreads();
        }
#pragma unroll
        for (int j = 0; j < 3; j++) {
            int o = pass * 96 + (wc * 3 + j) * 16 + ln;
            float bvf = Bias[288 + o];                         // bqv
#pragma unroll
            for (int r = 0; r < 4; r++) {
                int prow = p0 + wr * 16 + qd * 4 + r;
                float v = acc3[j][r] + bvf;
                u16 q = f2h(v);
                size_t pb = ((size_t)(img * M + prow)) * 192;
                if (o < 192) Qf[pb + o] = q;
                else         Vf[pb + o - 192] = q;
            }
        }
    }
}

// ---------------------------------------------------------------------------
// Attention: wave per pixel, lane = channel (64).  kk = l*3+j.
// ---------------------------------------------------------------------------
__global__ void attn_kernel(const u16* __restrict__ Qb, const u16* __restrict__ Vb,
                            const u16* __restrict__ Keys,
                            u16* __restrict__ Rh, u16* __restrict__ Rl)
{
    const int lane = threadIdx.x & 63;
    const int wv   = threadIdx.x >> 6;
    const int p = blockIdx.x * 4 + wv;
    const int b = blockIdx.y;

    float qv[15], vv[15];
#pragma unroll
    for (int l = 0; l < 5; l++) {
        size_t base = ((size_t)((l * 4 + b) * 9216 + p)) * 192;
#pragma unroll
        for (int j = 0; j < 3; j++) {
            qv[l * 3 + j] = h2f(Qb[base + j * 64 + lane]);
            vv[l * 3 + j] = h2f(Vb[base + j * 64 + lane]);
        }
    }
    size_t kb = ((size_t)(b * 9216 + p)) * 192;
#pragma unroll
    for (int i = 0; i < 3; i++) {
        float kf = h2f(Keys[kb + i * 64 + lane]);
        float lg[15];
#pragma unroll
        for (int t = 0; t < 15; t++) {
            float s = kf * qv[t];
#pragma unroll
            for (int m = 1; m < 64; m <<= 1) s += __shfl_xor(s, m, 64);
            lg[t] = s;
        }
        float mx = lg[0];
#pragma unroll
        for (int t = 1; t < 15; t++) mx = fmaxf(mx, lg[t]);
        float sum = 0.f;
#pragma unroll
        for (int t = 0; t < 15; t++) { lg[t] = __expf(lg[t] - mx); sum += lg[t]; }
        float inv = 1.f / sum;
        float ref = 0.f;
#pragma unroll
        for (int t = 0; t < 15; t++) ref += lg[t] * vv[t];
        u16 h, lo; fsplit(ref * inv, h, lo);
        Rh[kb + i * 64 + lane] = h;
        Rl[kb + i * 64 + lane] = lo;
    }
}

// Final: split pixel-major La -> channel-major f32 out[b][c][p], LDS-tiled.
__launch_bounds__(256)
__global__ void transpose_out(const u16* __restrict__ Lah, const u16* __restrict__ Lal,
                              float* __restrict__ out)
{
    __shared__ float t[32][33];
    const int b  = blockIdx.z;
    const int c0 = blockIdx.y * 32;
    const int p0 = blockIdx.x * 32;
    const int tid = threadIdx.x;
#pragma unroll
    for (int it = 0; it < 4; it++) {
        int i = it * 256 + tid;
        int cl = i & 31, pl = i >> 5;
        size_t idx = ((size_t)(b * 9216 + p0 + pl)) * 192 + c0 + cl;
        t[pl][cl] = b2f(Lah[idx]) + b2f(Lal[idx]);
    }
    __syncthreads();
#pragma unroll
    for (int it = 0; it < 4; it++) {
        int i = it * 256 + tid;
        int pl = i & 31, cl = i >> 5;
        out[((size_t)(b * 192 + c0 + cl)) * 9216 + p0 + pl] = t[pl][cl];
    }
}

__global__ void ws_too_small_kernel(float* out)
{
    int gid = blockIdx.x * 256 + threadIdx.x;
    out[gid] = 12345.0f;
}

// ---------------------------------------------------------------------------
extern "C" void kernel_launch(void* const* d_in, const int* in_sizes, int n_in,
                              void* d_out, int out_size, void* d_ws, size_t ws_size,
                              hipStream_t stream)
{
    u16* ws = (u16*)d_ws;
    // u16-element offsets (16B aligned)
    const size_t oXh   = 0;            // 35,389,440
    const size_t oXl   = 35389440;
    const size_t oQ    = 70778880;     // f16, aliased by P0
    const size_t oV    = 106168320;    // f16, P0 tail
    const size_t oLah  = 141557760;    // aliased by P2
    const size_t oLal  = 148635648;    // aliased by P3
    const size_t oKeys = 155713536;    // f16, aliased by P4
    const size_t oRh   = 162791424;
    const size_t oRl   = 169869312;
    const size_t oWh   = 176947200;    // 368,640
    const size_t oWl   = 177315840;    // 368,640
    const size_t oBias = 177684480;    // 1728 f32 = 3456 u16
    const size_t oWtab = 177687936;    // 1536 f32 = 3072
    const size_t oJtab = 177691008;    // 1536 i32 = 3072
    const size_t oFlag = 177694080;    // 16
    const size_t need_bytes = (size_t)177694096 * 2;   // ~355 MB

    if (ws_size < need_bytes) {
        ws_too_small_kernel<<<dim3(out_size / 256), dim3(256), 0, stream>>>((float*)d_out);
        return;
    }

    u16* Xh   = ws + oXh;
    u16* Xl   = ws + oXl;
    u16* Qf   = ws + oQ;
    u16* Vf   = ws + oV;
    u16* Lah  = ws + oLah;
    u16* Lal  = ws + oLal;
    u16* Keys = ws + oKeys;
    u16* Rh   = ws + oRh;
    u16* Rl   = ws + oRl;
    u16* Wh   = ws + oWh;
    u16* Wl   = ws + oWl;
    float* Bias = (float*)(ws + oBias);
    float* wtab = (float*)(ws + oWtab);
    int*   jtab = (int*)(ws + oJtab);
    int*   flag = (int*)(ws + oFlag);

    // staging aliases (consumed by upsample2 before host regions are written)
    u32* P0 = (u32*)(ws + oQ);      // 4*36864*192 u32 = 56.6M u16 < Q+V region
    u32* P2 = (u32*)(ws + oLah);
    u32* P3 = (u32*)(ws + oLal);
    u32* P4 = (u32*)(ws + oKeys);

    SrcPtrs S;
    S.wk1 = d_in[5];  S.bk1 = d_in[6];
    S.wk2 = d_in[7];  S.bk2 = d_in[8];
    S.wk3 = d_in[9];  S.bk3 = d_in[10];
    S.wq  = d_in[11]; S.bq  = d_in[12];
    S.wv  = d_in[13]; S.bv  = d_in[14];
    S.wcf = d_in[15]; S.bcf = d_in[16];
    S.we1 = d_in[17]; S.be1 = d_in[18];
    S.we2 = d_in[19]; S.be2 = d_in[20];
    S.wr1 = d_in[21]; S.br1 = d_in[22];
    S.wr2 = d_in[23]; S.br2 = d_in[24];
    S.bns = d_in[25]; S.bnt = d_in[26];

    dim3 blk(256);
    dim3 blk512(512);
    detect_dtype<<<dim3(1), dim3(64), 0, stream>>>((const u16*)d_in[0], flag);
    pack_weights<<<dim3(1447), blk, 0, stream>>>(S, Wh, Wl, Bias, flag);
    build_tables<<<dim3(1), dim3(384), 0, stream>>>(wtab, jtab);

    transpose_in<0><<<dim3(1152, 6, 4), blk, 0, stream>>>(d_in[0], 36864, P0, nullptr, nullptr, flag);
    transpose_in<1><<<dim3( 288, 6, 4), blk, 0, stream>>>(d_in[1],  9216, nullptr, Xh, Xl, flag);
    transpose_in<0><<<dim3(  72, 6, 4), blk, 0, stream>>>(d_in[2],  2304, P2, nullptr, nullptr, flag);
    transpose_in<0><<<dim3(  18, 6, 4), blk, 0, stream>>>(d_in[3],   576, P3, nullptr, nullptr, flag);
    transpose_in<0><<<dim3(   5, 6, 4), blk, 0, stream>>>(d_in[4],   144, P4, nullptr, nullptr, flag);
    upsample2<4><<<dim3(6912,  4), blk, 0, stream>>>(P0, nullptr, nullptr, wtab, jtab, Xh, Xl);
    upsample2<2><<<dim3(6912, 12), blk, 0, stream>>>(P2, P3, P4, wtab, jtab, Xh, Xl);

    for (int k = 0; k < 5; k++) {
        // fused: residual block (in-place Xf RMW) + Q|V projection from LDS.
        // k==4: Xf is dead afterwards -> skip the global Xf write.
        if (k < 4)
            fused_res_qv<1><<<dim3(144, 1, 20), blk512, 0, stream>>>(
                Xh, Xl, Wh, Wl, Bias, Qf, Vf);
        else
            fused_res_qv<0><<<dim3(144, 1, 20), blk512, 0, stream>>>(
                Xh, Xl, Wh, Wl, Bias, Qf, Vf);
        if (k == 0) {
            // cat_fuse (K=960, relu) -> Refs; fused emb -> La
            conv_gemm<12, 1, 2, 0><<<dim3(144, 1, 4), blk512, 0, stream>>>(
                Xh, Xl, Wh, Wl, Bias, 110592, 672, 960, 192, Rh, Rl);
            fused_mlp<2, 0><<<dim3(144, 1, 4), blk512, 0, stream>>>(
                Rh, Rl, Wh, Wl, Bias, 294912, 864, 313344, 960, Lah, Lal);
        }
        // keys: La -> Keys (f16, 3 projections packed)
        conv_gemm<12, 0, 0, 1><<<dim3(144, 1, 4), blk512, 0, stream>>>(
            Lah, Lal, Wh, Wl, Bias, 331776, 1152, 192, 192, Keys, nullptr);
        // attention -> Refs (split)
        attn_kernel<<<dim3(2304, 4), blk, 0, stream>>>(Qf, Vf, Keys, Rh, Rl);
        // fused emb: Refs -> gelu-hidden(96) -> La
        fused_mlp<2, 0><<<dim3(144, 1, 4), blk512, 0, stream>>>(
            Rh, Rl, Wh, Wl, Bias, 294912, 864, 313344, 960, Lah, Lal);
    }
    transpose_out<<<dim3(288, 6, 4), blk, 0, stream>>>(Lah, Lal, (float*)d_out);
}